// Round 18
// baseline (571.007 us; speedup 1.0000x reference)
//
#include <hip/hip_runtime.h>
#include <stdint.h>

using u16 = unsigned short;
typedef __bf16 bf16x8 __attribute__((ext_vector_type(8)));
typedef float f32x4 __attribute__((ext_vector_type(4)));
typedef u16 ushort8 __attribute__((ext_vector_type(8)));
typedef unsigned uint4v __attribute__((ext_vector_type(4)));
typedef unsigned uint2v __attribute__((ext_vector_type(2)));

// ===== session ledger (do not violate) =====
// attn_kernel on this toolchain:
//  - NO __builtin_amdgcn_s_setprio around MFMA (R5/R7: absmax 2.6e28)
//  - NO __launch_bounds__ second arg (R4/R11/R12: three bodies, all corrupt)
//  - NO v_permlane16_swap (R10: wrong lane routing)
//  - NO global_load_lds under wave-divergent branches (R2/R3)
//  - NO single-barrier multi-buffer pipelines (R15: 0.359)
//  - NO extra GLD16 per barrier interval in attn (R16: 0.116)
//  => ONLY the exact R14-green shape: 2 GLD16/thread, stage(nxt); barrier;
//     process(cur); barrier. Register-only deltas permitted.
//  R18 experiment: 2 q-frags per wave (register-only, same staging/sync).
// ===========================================

__device__ __forceinline__ u16 f2bf(float f) {
    unsigned u = __builtin_bit_cast(unsigned, f);
    return (u16)((u + 0x7fffu + ((u >> 16) & 1u)) >> 16);
}

__device__ __forceinline__ float bf2f(u16 v) {
    unsigned u = (unsigned)v << 16;
    return __builtin_bit_cast(float, u);
}

__device__ __forceinline__ float fexp2(float x) {
#if __has_builtin(__builtin_amdgcn_exp2f)
    return __builtin_amdgcn_exp2f(x);
#else
    return exp2f(x);
#endif
}

__device__ __forceinline__ unsigned cvt_pk_bf16(float lo, float hi) {
    unsigned r;
    asm("v_cvt_pk_bf16_f32 %0, %1, %2" : "=v"(r) : "v"(lo), "v"(hi));
    return r;
}

// global->LDS direct copy, 16B per lane. LDS dest is wave-uniform base + lane*16.
#define GLD16(gptr, lptr) __builtin_amdgcn_global_load_lds( \
    (const __attribute__((address_space(1))) void*)(unsigned long long)(gptr), \
    (__attribute__((address_space(3))) void*)(unsigned)(unsigned long long)(lptr), 16, 0, 0)

// ---------------- conversion kernels ----------------

__global__ void convert_bf16(const float* __restrict__ in, u16* __restrict__ out) {
    int gid = blockIdx.x * 256 + threadIdx.x;      // 8 f32 per thread
    const float4* in4 = (const float4*)in;
    float4 a = in4[2 * gid], b = in4[2 * gid + 1];
    ushort8 o;
    o[0] = f2bf(a.x); o[1] = f2bf(a.y); o[2] = f2bf(a.z); o[3] = f2bf(a.w);
    o[4] = f2bf(b.x); o[5] = f2bf(b.y); o[6] = f2bf(b.z); o[7] = f2bf(b.w);
    *(ushort8*)(out + (size_t)gid * 8) = o;
}

// out[C][R] = bf16(in[R][C])  -- 64x64 LDS tile transpose
__global__ void transpose_convert(const float* __restrict__ in, u16* __restrict__ out,
                                  int R, int C) {
    __shared__ u16 sT[64][65];
    const int c0 = blockIdx.x << 6, r0 = blockIdx.y << 6;
    const int tid = threadIdx.x;
#pragma unroll
    for (int rep = 0; rep < 16; rep++) {
        int idx = rep * 256 + tid;
        int r = idx >> 6, c = idx & 63;
        sT[c][r] = f2bf(in[(size_t)(r0 + r) * C + c0 + c]);
    }
    __syncthreads();
#pragma unroll
    for (int rep = 0; rep < 16; rep++) {
        int idx = rep * 256 + tid;
        int r = idx >> 6, c = idx & 63;
        out[(size_t)(c0 + r) * R + r0 + c] = sT[r][c];
    }
}

// maskbits[i][w] bit (j&31) = (mask[i][2j+1] != 0), j = resized col index
__global__ void mask_pack(const float* __restrict__ mask, unsigned* __restrict__ mw) {
    int gid = blockIdx.x * 256 + threadIdx.x;      // 4096*2048 threads
    int i = gid >> 11, j = gid & 2047;
    float v = mask[(size_t)i * 4096 + 2 * j + 1];
    unsigned long long b = __ballot(v != 0.0f);
    int lane = threadIdx.x & 63;
    if (lane == 0)       mw[(size_t)i * 64 + (j >> 5)] = (unsigned)b;
    else if (lane == 32) mw[(size_t)i * 64 + (j >> 5)] = (unsigned)(b >> 32);
}

// ---------------- NT GEMM: C[i][j] = sum_k A[i][k]*B[j][k] ----------------
// A [M][K] row-major bf16, B [N][K] row-major bf16. 128x128 tile, BK=32, dbuf LDS.
// grid = (N/128, M/128, batches)

template <bool OUT_BF16, bool ADD_BIAS>
__global__ __launch_bounds__(256) void gemm_nt(
    const u16* __restrict__ A, int lda, long long sA,
    const u16* __restrict__ B, int ldb, long long sB,
    void* __restrict__ Cp, int ldc, long long sC,
    const float* __restrict__ bias, int K) {
    __shared__ __align__(16) u16 lds[2][2][4][128][8];   // [buf][mat][kblk][row][8] = 32KB
    const int bz = blockIdx.z;
    const u16* Ab = A + (size_t)sA * bz;
    const u16* Bb = B + (size_t)sB * bz;
    const int m0 = blockIdx.y << 7, n0 = blockIdx.x << 7;
    const int tid = threadIdx.x, wave = tid >> 6, lane = tid & 63;
    const int kg = lane >> 4, lr = lane & 15;
    const int wr = (wave >> 1) << 6, wc = (wave & 1) << 6;
    const int nT = K >> 5;
    f32x4 acc[4][4] = {};

    // prologue: stage tile 0 into buf 0. wave stages kblk==wave, rows i*64+lane.
#pragma unroll
    for (int i = 0; i < 2; i++) {
        int row = i * 64 + lane;
        GLD16(Ab + (size_t)(m0 + row) * lda + wave * 8, &lds[0][0][wave][i * 64][0]);
        GLD16(Bb + (size_t)(n0 + row) * ldb + wave * 8, &lds[0][1][wave][i * 64][0]);
    }
    for (int t = 0; t < nT; ++t) {
        const int cur = t & 1;
        if (t + 1 < nT) {
            const int nxt = cur ^ 1;
            const int koff = (t + 1) << 5;
#pragma unroll
            for (int i = 0; i < 2; i++) {
                int row = i * 64 + lane;
                GLD16(Ab + (size_t)(m0 + row) * lda + koff + wave * 8, &lds[nxt][0][wave][i * 64][0]);
                GLD16(Bb + (size_t)(n0 + row) * ldb + koff + wave * 8, &lds[nxt][1][wave][i * 64][0]);
            }
        }
        __syncthreads();   // drains vmcnt -> buf[cur] ready
        bf16x8 af[4], bfv[4];
#pragma unroll
        for (int mi = 0; mi < 4; mi++)
            af[mi] = *(const bf16x8*)&lds[cur][0][kg][wr + mi * 16 + lr][0];
#pragma unroll
        for (int ni = 0; ni < 4; ni++)
            bfv[ni] = *(const bf16x8*)&lds[cur][1][kg][wc + ni * 16 + lr][0];
#pragma unroll
        for (int mi = 0; mi < 4; mi++)
#pragma unroll
            for (int ni = 0; ni < 4; ni++)
                acc[mi][ni] = __builtin_amdgcn_mfma_f32_16x16x32_bf16(af[mi], bfv[ni], acc[mi][ni], 0, 0, 0);
        __syncthreads();   // all reads of buf[cur] done before it is re-staged
    }

    if constexpr (OUT_BF16) {
        u16* C = (u16*)Cp + (size_t)sC * bz;
#pragma unroll
        for (int mi = 0; mi < 4; mi++)
#pragma unroll
            for (int ni = 0; ni < 4; ni++)
#pragma unroll
                for (int r = 0; r < 4; r++) {
                    int gr = m0 + wr + mi * 16 + kg * 4 + r;
                    int gc = n0 + wc + ni * 16 + lr;
                    C[(size_t)gr * ldc + gc] = f2bf(acc[mi][ni][r]);
                }
    } else {
        float* C = (float*)Cp + (size_t)sC * bz;
#pragma unroll
        for (int mi = 0; mi < 4; mi++)
#pragma unroll
            for (int ni = 0; ni < 4; ni++)
#pragma unroll
                for (int r = 0; r < 4; r++) {
                    int gr = m0 + wr + mi * 16 + kg * 4 + r;
                    int gc = n0 + wc + ni * 16 + lr;
                    float v = acc[mi][ni][r];
                    if constexpr (ADD_BIAS) v += bias[gc];
                    C[(size_t)gr * ldc + gc] = v;
                }
    }
}

// ---- split-K variant: bz in [0,4) = (bsel = bz>>1, ks = bz&1). bf16 partials.
// Cpart[bz][i][j] = sum_{k in half ks} A[bsel-slice][i][k] * B[bsel-slice][j][k]
__global__ __launch_bounds__(256) void gemm_nt_splitk(
    const u16* __restrict__ A, int lda, long long sAb,
    const u16* __restrict__ B, int ldb, long long sBb,
    u16* __restrict__ Cp, int ldc, long long sC, int K2) {
    __shared__ __align__(16) u16 lds[2][2][4][128][8];
    const int bz = blockIdx.z, bsel = bz >> 1, ks = bz & 1;
    const u16* Ab = A + (size_t)sAb * bsel + (size_t)ks * K2;
    const u16* Bb = B + (size_t)sBb * bsel + (size_t)ks * K2;
    const int m0 = blockIdx.y << 7, n0 = blockIdx.x << 7;
    const int tid = threadIdx.x, wave = tid >> 6, lane = tid & 63;
    const int kg = lane >> 4, lr = lane & 15;
    const int wr = (wave >> 1) << 6, wc = (wave & 1) << 6;
    const int nT = K2 >> 5;
    f32x4 acc[4][4] = {};

#pragma unroll
    for (int i = 0; i < 2; i++) {
        int row = i * 64 + lane;
        GLD16(Ab + (size_t)(m0 + row) * lda + wave * 8, &lds[0][0][wave][i * 64][0]);
        GLD16(Bb + (size_t)(n0 + row) * ldb + wave * 8, &lds[0][1][wave][i * 64][0]);
    }
    for (int t = 0; t < nT; ++t) {
        const int cur = t & 1;
        if (t + 1 < nT) {
            const int nxt = cur ^ 1;
            const int koff = (t + 1) << 5;
#pragma unroll
            for (int i = 0; i < 2; i++) {
                int row = i * 64 + lane;
                GLD16(Ab + (size_t)(m0 + row) * lda + koff + wave * 8, &lds[nxt][0][wave][i * 64][0]);
                GLD16(Bb + (size_t)(n0 + row) * ldb + koff + wave * 8, &lds[nxt][1][wave][i * 64][0]);
            }
        }
        __syncthreads();
        bf16x8 af[4], bfv[4];
#pragma unroll
        for (int mi = 0; mi < 4; mi++)
            af[mi] = *(const bf16x8*)&lds[cur][0][kg][wr + mi * 16 + lr][0];
#pragma unroll
        for (int ni = 0; ni < 4; ni++)
            bfv[ni] = *(const bf16x8*)&lds[cur][1][kg][wc + ni * 16 + lr][0];
#pragma unroll
        for (int mi = 0; mi < 4; mi++)
#pragma unroll
            for (int ni = 0; ni < 4; ni++)
                acc[mi][ni] = __builtin_amdgcn_mfma_f32_16x16x32_bf16(af[mi], bfv[ni], acc[mi][ni], 0, 0, 0);
        __syncthreads();
    }

    u16* C = Cp + (size_t)sC * bz;
#pragma unroll
    for (int mi = 0; mi < 4; mi++)
#pragma unroll
        for (int ni = 0; ni < 4; ni++)
#pragma unroll
            for (int r = 0; r < 4; r++) {
                int gr = m0 + wr + mi * 16 + kg * 4 + r;
                int gc = n0 + wc + ni * 16 + lr;
                C[(size_t)gr * ldc + gc] = f2bf(acc[mi][ni][r]);
            }
}

// dst[d] = bf16( p[(2b)S + r] + p[(2b+1)S + r] ),  d = b*S + r, S = 2^21
__global__ void combine_bf16(const u16* __restrict__ p, u16* __restrict__ dst) {
    int gid = blockIdx.x * 256 + threadIdx.x;   // 524288 threads, 8 elems each
    size_t d = (size_t)gid * 8;
    size_t b = d >> 21, r = d & (((size_t)1 << 21) - 1);
    const ushort8 a = *(const ushort8*)(p + ((b * 2) << 21) + r);
    const ushort8 c = *(const ushort8*)(p + ((b * 2 + 1) << 21) + r);
    ushort8 o;
#pragma unroll
    for (int i = 0; i < 8; i++) o[i] = f2bf(bf2f(a[i]) + bf2f(c[i]));
    *(ushort8*)(dst + d) = o;
}

// ---------------- flash attention over compressed K/V (R17-green + 2 q-frags) --
// Block: 4 waves x 32 q rows each = 128 rows/block; grid (bh=32, qchunk=32).
// Staging/sync/xform identical to R17-green (2 GLD16/thread; stage(nxt);
// barrier; process; barrier). SOLE delta: each wave processes TWO q-frag sets
// (frag1 = frag0 rows +16) against the same staged K/V tile -> GLD16 issues,
// barriers, ds_reads per unit work halve. Register-only expansion.

__global__ __launch_bounds__(256) void attn_kernel(
    const u16* __restrict__ q, const u16* __restrict__ kb,
    const u16* __restrict__ vt, const unsigned* __restrict__ mw,
    u16* __restrict__ ao) {
    __shared__ __align__(16) u16 sK[2][8][32][8];   // [buf][dh8][kp][8] 4KB/buf
    __shared__ __align__(16) u16 sV[2][4][64][8];   // [buf][kp8][dh][8] 4KB/buf
    const int tid = threadIdx.x;
    const int wave = tid >> 6, lane = tid & 63, kg = lane >> 4, lr = lane & 15;
    const int b = blockIdx.x >> 4, h = blockIdx.x & 15;
    const int nrow = (blockIdx.y << 7) + wave * 32;

    const u16* qrow = q + (size_t)(b * 4096 + nrow + lr) * 1024 + h * 64 + kg * 8;
    const bf16x8 aq00 = *(const bf16x8*)qrow;
    const bf16x8 aq01 = *(const bf16x8*)(qrow + 32);
    const bf16x8 aq10 = *(const bf16x8*)(qrow + 16 * 1024);
    const bf16x8 aq11 = *(const bf16x8*)(qrow + 16 * 1024 + 32);
    const u16* kh = kb + (size_t)b * 2048 * 1024 + h * 64;
    const u16* vh = vt + ((size_t)b * 1024 + (size_t)h * 64) * 2048;
    const unsigned* mrow0 = mw + (size_t)(nrow + lr) * 64;
    const unsigned* mrow1 = mrow0 + 16 * 64;

    // branch-free staging addresses (fixed per thread; only j0 varies)
    const u16* ksrc = kh + (size_t)(lane & 31) * 1024 + (wave * 2 + (lane >> 5)) * 8;
    const u16* vsrc = vh + (size_t)lane * 2048 + wave * 8;

    f32x4 o0[4] = {};     // frag0: O[q=nrow+lr][dh = f*16 + kg*4 + r]
    f32x4 o1[4] = {};     // frag1: O[q=nrow+16+lr][...]
    float lsum0 = 0.0f, lsum1 = 0.0f;
    const bool low16 = (lane & 16) == 0;

    auto stage = [&](int bf, int j0) {
        GLD16(ksrc + (size_t)j0 * 1024, &sK[bf][wave * 2][0][0]);
        GLD16(vsrc + j0, &sV[bf][wave][0][0]);
    };

    auto xform = [&](const float p0[4], const float p1[4]) -> bf16x8 {
        unsigned X0 = cvt_pk_bf16(p0[0], p0[1]);
        unsigned X1 = cvt_pk_bf16(p0[2], p0[3]);
        unsigned Y0 = cvt_pk_bf16(p1[0], p1[1]);
        unsigned Y1 = cvt_pk_bf16(p1[2], p1[3]);
        asm volatile("v_permlane32_swap_b32 %0, %1" : "+v"(X0), "+v"(Y0));
        asm volatile("v_permlane32_swap_b32 %0, %1" : "+v"(X1), "+v"(Y1));
        unsigned sX0 = (unsigned)__shfl_xor((int)X0, 16);
        unsigned sY0 = (unsigned)__shfl_xor((int)Y0, 16);
        unsigned sX1 = (unsigned)__shfl_xor((int)X1, 16);
        unsigned sY1 = (unsigned)__shfl_xor((int)Y1, 16);
        uint4v wv;
        wv[0] = low16 ? X0 : sY0;
        wv[1] = low16 ? X1 : sY1;
        wv[2] = low16 ? sX0 : Y0;
        wv[3] = low16 ? sX1 : Y1;
        return __builtin_bit_cast(bf16x8, wv);
    };

    auto process = [&](int cur, unsigned wd0, unsigned wd1) {
        const bf16x8 k0a = *(const bf16x8*)&sK[cur][kg][lr][0];
        const bf16x8 k0b = *(const bf16x8*)&sK[cur][4 + kg][lr][0];
        const bf16x8 k1a = *(const bf16x8*)&sK[cur][kg][16 + lr][0];
        const bf16x8 k1b = *(const bf16x8*)&sK[cur][4 + kg][16 + lr][0];
        const bf16x8 v0 = *(const bf16x8*)&sV[cur][kg][lr][0];
        const bf16x8 v1 = *(const bf16x8*)&sV[cur][kg][16 + lr][0];
        const bf16x8 v2 = *(const bf16x8*)&sV[cur][kg][32 + lr][0];
        const bf16x8 v3 = *(const bf16x8*)&sV[cur][kg][48 + lr][0];

        f32x4 s00 = {}, s01 = {}, s10 = {}, s11 = {};
        s00 = __builtin_amdgcn_mfma_f32_16x16x32_bf16(k0a, aq00, s00, 0, 0, 0);
        s00 = __builtin_amdgcn_mfma_f32_16x16x32_bf16(k0b, aq01, s00, 0, 0, 0);
        s01 = __builtin_amdgcn_mfma_f32_16x16x32_bf16(k1a, aq00, s01, 0, 0, 0);
        s01 = __builtin_amdgcn_mfma_f32_16x16x32_bf16(k1b, aq01, s01, 0, 0, 0);
        s10 = __builtin_amdgcn_mfma_f32_16x16x32_bf16(k0a, aq10, s10, 0, 0, 0);
        s10 = __builtin_amdgcn_mfma_f32_16x16x32_bf16(k0b, aq11, s10, 0, 0, 0);
        s11 = __builtin_amdgcn_mfma_f32_16x16x32_bf16(k1a, aq10, s11, 0, 0, 0);
        s11 = __builtin_amdgcn_mfma_f32_16x16x32_bf16(k1b, aq11, s11, 0, 0, 0);

        const float C = 0.18033688f;   // 0.125 * log2(e)
        const unsigned mb00 = wd0 >> (kg * 4), mb01 = wd0 >> (16 + kg * 4);
        const unsigned mb10 = wd1 >> (kg * 4), mb11 = wd1 >> (16 + kg * 4);
        float p00[4], p01[4], p10[4], p11[4];
#pragma unroll
        for (int r = 0; r < 4; r++) {
            p00[r] = fexp2(((mb00 >> r) & 1u) ? -1.0e30f : s00[r] * C);
            p01[r] = fexp2(((mb01 >> r) & 1u) ? -1.0e30f : s01[r] * C);
            p10[r] = fexp2(((mb10 >> r) & 1u) ? -1.0e30f : s10[r] * C);
            p11[r] = fexp2(((mb11 >> r) & 1u) ? -1.0e30f : s11[r] * C);
            lsum0 += p00[r] + p01[r];
            lsum1 += p10[r] + p11[r];
        }
        const bf16x8 W0 = xform(p00, p01);
        const bf16x8 W1 = xform(p10, p11);
        o0[0] = __builtin_amdgcn_mfma_f32_16x16x32_bf16(v0, W0, o0[0], 0, 0, 0);
        o0[1] = __builtin_amdgcn_mfma_f32_16x16x32_bf16(v1, W0, o0[1], 0, 0, 0);
        o0[2] = __builtin_amdgcn_mfma_f32_16x16x32_bf16(v2, W0, o0[2], 0, 0, 0);
        o0[3] = __builtin_amdgcn_mfma_f32_16x16x32_bf16(v3, W0, o0[3], 0, 0, 0);
        o1[0] = __builtin_amdgcn_mfma_f32_16x16x32_bf16(v0, W1, o1[0], 0, 0, 0);
        o1[1] = __builtin_amdgcn_mfma_f32_16x16x32_bf16(v1, W1, o1[1], 0, 0, 0);
        o1[2] = __builtin_amdgcn_mfma_f32_16x16x32_bf16(v2, W1, o1[2], 0, 0, 0);
        o1[3] = __builtin_amdgcn_mfma_f32_16x16x32_bf16(v3, W1, o1[3], 0, 0, 0);
    };

    stage(0, 0);
    unsigned wdc0 = mrow0[0], wdc1 = mrow1[0];
    for (int t = 0; t < 64; ++t) {
        const int cur = t & 1;
        if (t < 63) stage(cur ^ 1, (t + 1) * 32);
        unsigned wdn0 = (t < 63) ? mrow0[t + 1] : 0u;   // prefetch next mask words
        unsigned wdn1 = (t < 63) ? mrow1[t + 1] : 0u;
        __syncthreads();   // drains vmcnt -> buf[cur] ready (and wdn*)
        process(cur, wdc0, wdc1);
        wdc0 = wdn0;
        wdc1 = wdn1;
        __syncthreads();   // all reads of buf[cur] done before re-stage
    }

    lsum0 += __shfl_xor(lsum0, 16); lsum0 += __shfl_xor(lsum0, 32);
    lsum1 += __shfl_xor(lsum1, 16); lsum1 += __shfl_xor(lsum1, 32);
    const float inv0 = 1.0f / lsum0, inv1 = 1.0f / lsum1;

    u16* orow0 = ao + (size_t)(b * 4096 + nrow + lr) * 1024 + h * 64 + kg * 4;
    u16* orow1 = orow0 + 16 * 1024;
#pragma unroll
    for (int f = 0; f < 4; f++) {
        uint2v st0, st1;
        st0[0] = cvt_pk_bf16(o0[f][0] * inv0, o0[f][1] * inv0);
        st0[1] = cvt_pk_bf16(o0[f][2] * inv0, o0[f][3] * inv0);
        st1[0] = cvt_pk_bf16(o1[f][0] * inv1, o1[f][1] * inv1);
        st1[1] = cvt_pk_bf16(o1[f][2] * inv1, o1[f][3] * inv1);
        *(uint2v*)(orow0 + f * 16) = st0;
        *(uint2v*)(orow1 + f * 16) = st1;
    }
}

// ---------------- launcher ----------------

extern "C" void kernel_launch(void* const* d_in, const int* in_sizes, int n_in,
                              void* d_out, int out_size, void* d_ws, size_t ws_size,
                              hipStream_t stream) {
    const float* x    = (const float*)d_in[0];
    const float* mask = (const float*)d_in[1];
    const float* Wq   = (const float*)d_in[2];
    const float* Wk   = (const float*)d_in[3];
    const float* Wv   = (const float*)d_in[4];
    const float* Wo   = (const float*)d_in[5];
    const float* bo   = (const float*)d_in[6];
    const float* pk   = (const float*)d_in[7];
    const float* pv   = (const float*)d_in[8];
    float* out = (float*)d_out;

    char* w = (char*)d_ws;
    auto alloc = [&](size_t bytes) { void* p = w; w += (bytes + 255) & ~(size_t)255; return p; };
    u16* xb   = (u16*)alloc((size_t)8192 * 1024 * 2);
    u16* qb   = (u16*)alloc((size_t)8192 * 1024 * 2);
    u16* xkT  = (u16*)alloc((size_t)1024 * 8192 * 2);   // [xkT|xvT] contiguous:
    u16* xvT  = (u16*)alloc((size_t)1024 * 8192 * 2);   // fused M=2048 GEMM output
    u16* WqT  = (u16*)alloc((size_t)1024 * 1024 * 2);
    u16* WkT  = (u16*)alloc((size_t)1024 * 1024 * 2);   // [WkT|WvT] contiguous:
    u16* WvT  = (u16*)alloc((size_t)1024 * 1024 * 2);   // fused GEMM A-operand
    u16* WoT  = (u16*)alloc((size_t)1024 * 1024 * 2);
    u16* pkT  = (u16*)alloc((size_t)2048 * 4096 * 2);
    u16* pvT  = (u16*)alloc((size_t)2048 * 4096 * 2);
    u16* kbuf = (u16*)alloc((size_t)2 * 2048 * 1024 * 2);
    u16* vtb  = (u16*)alloc((size_t)2 * 1024 * 2048 * 2);
    unsigned* mw = (unsigned*)alloc((size_t)4096 * 64 * 4);
    (void)alloc((size_t)128 * 1024);   // guard pad
    u16* ao   = xb;   // alias: xb dead after q-proj; attention writes after that
    u16* pbuf = qb;   // alias: 4 x 2048x1024 bf16 partials = 16MB, dead before q-proj
    (void)xvT;

    convert_bf16<<<4096, 256, 0, stream>>>(x, xb);
    transpose_convert<<<dim3(16, 16), 256, 0, stream>>>(Wq, WqT, 1024, 1024);
    transpose_convert<<<dim3(16, 16), 256, 0, stream>>>(Wk, WkT, 1024, 1024);
    transpose_convert<<<dim3(16, 16), 256, 0, stream>>>(Wv, WvT, 1024, 1024);
    transpose_convert<<<dim3(16, 16), 256, 0, stream>>>(Wo, WoT, 1024, 1024);
    transpose_convert<<<dim3(32, 64), 256, 0, stream>>>(pk, pkT, 4096, 2048);
    transpose_convert<<<dim3(32, 64), 256, 0, stream>>>(pv, pvT, 4096, 2048);
    mask_pack<<<32768, 256, 0, stream>>>(mask, mw);

    // fused [xkT|xvT] = [WkT|WvT](M=2048) x B(xb) : [2048,8192], one launch
    gemm_nt<true, false><<<dim3(64, 16, 1), 256, 0, stream>>>(WkT, 1024, 0, xb, 1024, 0, xkT, 8192, 0, nullptr, 1024);

    // k[b] = proj_k^T @ xk[b] : split-K x2 -> bf16 partials -> combine
    gemm_nt_splitk<<<dim3(8, 16, 4), 256, 0, stream>>>(pkT, 4096, 0, xkT, 8192, 4096,
                                                       pbuf, 1024, (long long)1 << 21, 2048);
    combine_bf16<<<2048, 256, 0, stream>>>(pbuf, kbuf);
    // vT[b] = xv[b]^T @ proj_v : split-K x2
    gemm_nt_splitk<<<dim3(16, 8, 4), 256, 0, stream>>>(xvT, 8192, 4096, pvT, 4096, 0,
                                                       pbuf, 2048, (long long)1 << 21, 2048);
    combine_bf16<<<2048, 256, 0, stream>>>(pbuf, vtb);

    // q = x @ Wq (runs AFTER combines: qb overlays pbuf)
    gemm_nt<true, false><<<dim3(8, 64, 1), 256, 0, stream>>>(xb, 1024, 0, WqT, 1024, 0, qb, 1024, 0, nullptr, 1024);

    // grid (bh=32, qchunk=32): XCD = bh%8 (L2 locality); 128 q rows per block
    attn_kernel<<<dim3(32, 32), 256, 0, stream>>>(qb, kbuf, vtb, mw, ao);

    // out = ao @ Wo + bo (f32 out)
    gemm_nt<false, true><<<dim3(8, 64, 1), 256, 0, stream>>>(ao, 1024, 0, WoT, 1024, 0, out, 1024, 0, bo, 1024);
}

// Round 19
// 564.156 us; speedup vs baseline: 1.0121x; 1.0121x over previous
//
#include <hip/hip_runtime.h>
#include <stdint.h>

using u16 = unsigned short;
typedef __bf16 bf16x8 __attribute__((ext_vector_type(8)));
typedef float f32x4 __attribute__((ext_vector_type(4)));
typedef u16 ushort8 __attribute__((ext_vector_type(8)));
typedef unsigned uint4v __attribute__((ext_vector_type(4)));
typedef unsigned uint2v __attribute__((ext_vector_type(2)));

// ===== session ledger (do not violate) =====
// attn_kernel on this toolchain:
//  - NO __builtin_amdgcn_s_setprio around MFMA (R5/R7: absmax 2.6e28)
//  - NO __launch_bounds__ second arg (R4/R11/R12: three bodies, all corrupt)
//  - NO v_permlane16_swap (R10: wrong lane routing)
//  - NO global_load_lds under wave-divergent branches (R2/R3)
//  - NO single-barrier multi-buffer pipelines (R15: 0.359)
//  - NO extra GLD16 per barrier interval in attn (R16: 0.116)
//  - 2-q-frag/wave: green but SLOWER (R18: occupancy 48->23%, +18us). Reverted.
//  => attn is frozen at the R17-green shape (204.5 us).
// ===========================================

__device__ __forceinline__ u16 f2bf(float f) {
    unsigned u = __builtin_bit_cast(unsigned, f);
    return (u16)((u + 0x7fffu + ((u >> 16) & 1u)) >> 16);
}

__device__ __forceinline__ float bf2f(u16 v) {
    unsigned u = (unsigned)v << 16;
    return __builtin_bit_cast(float, u);
}

__device__ __forceinline__ float fexp2(float x) {
#if __has_builtin(__builtin_amdgcn_exp2f)
    return __builtin_amdgcn_exp2f(x);
#else
    return exp2f(x);
#endif
}

__device__ __forceinline__ unsigned cvt_pk_bf16(float lo, float hi) {
    unsigned r;
    asm("v_cvt_pk_bf16_f32 %0, %1, %2" : "=v"(r) : "v"(lo), "v"(hi));
    return r;
}

// global->LDS direct copy, 16B per lane. LDS dest is wave-uniform base + lane*16.
#define GLD16(gptr, lptr) __builtin_amdgcn_global_load_lds( \
    (const __attribute__((address_space(1))) void*)(unsigned long long)(gptr), \
    (__attribute__((address_space(3))) void*)(unsigned)(unsigned long long)(lptr), 16, 0, 0)

// ---------------- conversion kernels ----------------

__global__ void convert_bf16(const float* __restrict__ in, u16* __restrict__ out) {
    int gid = blockIdx.x * 256 + threadIdx.x;      // 8 f32 per thread
    const float4* in4 = (const float4*)in;
    float4 a = in4[2 * gid], b = in4[2 * gid + 1];
    ushort8 o;
    o[0] = f2bf(a.x); o[1] = f2bf(a.y); o[2] = f2bf(a.z); o[3] = f2bf(a.w);
    o[4] = f2bf(b.x); o[5] = f2bf(b.y); o[6] = f2bf(b.z); o[7] = f2bf(b.w);
    *(ushort8*)(out + (size_t)gid * 8) = o;
}

// out[C][R] = bf16(in[R][C])  -- 64x64 LDS tile transpose
__global__ void transpose_convert(const float* __restrict__ in, u16* __restrict__ out,
                                  int R, int C) {
    __shared__ u16 sT[64][65];
    const int c0 = blockIdx.x << 6, r0 = blockIdx.y << 6;
    const int tid = threadIdx.x;
#pragma unroll
    for (int rep = 0; rep < 16; rep++) {
        int idx = rep * 256 + tid;
        int r = idx >> 6, c = idx & 63;
        sT[c][r] = f2bf(in[(size_t)(r0 + r) * C + c0 + c]);
    }
    __syncthreads();
#pragma unroll
    for (int rep = 0; rep < 16; rep++) {
        int idx = rep * 256 + tid;
        int r = idx >> 6, c = idx & 63;
        out[(size_t)(c0 + r) * R + r0 + c] = sT[r][c];
    }
}

// maskbits[i][w] bit (j&31) = (mask[i][2j+1] != 0), j = resized col index
__global__ void mask_pack(const float* __restrict__ mask, unsigned* __restrict__ mw) {
    int gid = blockIdx.x * 256 + threadIdx.x;      // 4096*2048 threads
    int i = gid >> 11, j = gid & 2047;
    float v = mask[(size_t)i * 4096 + 2 * j + 1];
    unsigned long long b = __ballot(v != 0.0f);
    int lane = threadIdx.x & 63;
    if (lane == 0)       mw[(size_t)i * 64 + (j >> 5)] = (unsigned)b;
    else if (lane == 32) mw[(size_t)i * 64 + (j >> 5)] = (unsigned)(b >> 32);
}

// ---------------- NT GEMM: C[i][j] = sum_k A[i][k]*B[j][k] ----------------
// A [M][K] row-major bf16, B [N][K] row-major bf16. 128x128 tile, BK=32, dbuf LDS.
// grid = (N/128, M/128, batches)

template <bool OUT_BF16, bool ADD_BIAS>
__global__ __launch_bounds__(256) void gemm_nt(
    const u16* __restrict__ A, int lda, long long sA,
    const u16* __restrict__ B, int ldb, long long sB,
    void* __restrict__ Cp, int ldc, long long sC,
    const float* __restrict__ bias, int K) {
    __shared__ __align__(16) u16 lds[2][2][4][128][8];   // [buf][mat][kblk][row][8] = 32KB
    const int bz = blockIdx.z;
    const u16* Ab = A + (size_t)sA * bz;
    const u16* Bb = B + (size_t)sB * bz;
    const int m0 = blockIdx.y << 7, n0 = blockIdx.x << 7;
    const int tid = threadIdx.x, wave = tid >> 6, lane = tid & 63;
    const int kg = lane >> 4, lr = lane & 15;
    const int wr = (wave >> 1) << 6, wc = (wave & 1) << 6;
    const int nT = K >> 5;
    f32x4 acc[4][4] = {};

    // prologue: stage tile 0 into buf 0. wave stages kblk==wave, rows i*64+lane.
#pragma unroll
    for (int i = 0; i < 2; i++) {
        int row = i * 64 + lane;
        GLD16(Ab + (size_t)(m0 + row) * lda + wave * 8, &lds[0][0][wave][i * 64][0]);
        GLD16(Bb + (size_t)(n0 + row) * ldb + wave * 8, &lds[0][1][wave][i * 64][0]);
    }
    for (int t = 0; t < nT; ++t) {
        const int cur = t & 1;
        if (t + 1 < nT) {
            const int nxt = cur ^ 1;
            const int koff = (t + 1) << 5;
#pragma unroll
            for (int i = 0; i < 2; i++) {
                int row = i * 64 + lane;
                GLD16(Ab + (size_t)(m0 + row) * lda + koff + wave * 8, &lds[nxt][0][wave][i * 64][0]);
                GLD16(Bb + (size_t)(n0 + row) * ldb + koff + wave * 8, &lds[nxt][1][wave][i * 64][0]);
            }
        }
        __syncthreads();   // drains vmcnt -> buf[cur] ready
        bf16x8 af[4], bfv[4];
#pragma unroll
        for (int mi = 0; mi < 4; mi++)
            af[mi] = *(const bf16x8*)&lds[cur][0][kg][wr + mi * 16 + lr][0];
#pragma unroll
        for (int ni = 0; ni < 4; ni++)
            bfv[ni] = *(const bf16x8*)&lds[cur][1][kg][wc + ni * 16 + lr][0];
#pragma unroll
        for (int mi = 0; mi < 4; mi++)
#pragma unroll
            for (int ni = 0; ni < 4; ni++)
                acc[mi][ni] = __builtin_amdgcn_mfma_f32_16x16x32_bf16(af[mi], bfv[ni], acc[mi][ni], 0, 0, 0);
        __syncthreads();   // all reads of buf[cur] done before it is re-staged
    }

    if constexpr (OUT_BF16) {
        u16* C = (u16*)Cp + (size_t)sC * bz;
#pragma unroll
        for (int mi = 0; mi < 4; mi++)
#pragma unroll
            for (int ni = 0; ni < 4; ni++)
#pragma unroll
                for (int r = 0; r < 4; r++) {
                    int gr = m0 + wr + mi * 16 + kg * 4 + r;
                    int gc = n0 + wc + ni * 16 + lr;
                    C[(size_t)gr * ldc + gc] = f2bf(acc[mi][ni][r]);
                }
    } else {
        float* C = (float*)Cp + (size_t)sC * bz;
#pragma unroll
        for (int mi = 0; mi < 4; mi++)
#pragma unroll
            for (int ni = 0; ni < 4; ni++)
#pragma unroll
                for (int r = 0; r < 4; r++) {
                    int gr = m0 + wr + mi * 16 + kg * 4 + r;
                    int gc = n0 + wc + ni * 16 + lr;
                    float v = acc[mi][ni][r];
                    if constexpr (ADD_BIAS) v += bias[gc];
                    C[(size_t)gr * ldc + gc] = v;
                }
    }
}

// ---- merged split-K for BOTH compress GEMMs in one launch ----
// z in [0,8): g = z>>2 (0 = K-compress, 1 = V-compress), bsel = (z>>1)&1,
// ks = z&1. Pointer/geometry selection is BLOCK-UNIFORM (scalar branch on
// blockIdx only; no barriers inside branches). Inner loop identical to the
// proven splitk body. Partials go to slot z of Cp (stride 2^21 bf16).
//   K-compress: C[2048,1024] = pkT(lda 4096) x xkT-slice(ldb 8192), 8x16 tiles
//   V-compress: C[1024,2048] = xvT-slice(lda 8192) x pvT(ldb 4096), 16x8 tiles
// grid = (128, 1, 8); tx decodes (m0, n0) per-gemm.
__global__ __launch_bounds__(256) void gemm_nt_splitk2(
    const u16* __restrict__ pkT, const u16* __restrict__ xkT,
    const u16* __restrict__ xvT, const u16* __restrict__ pvT,
    u16* __restrict__ Cp) {
    __shared__ __align__(16) u16 lds[2][2][4][128][8];
    const int z = blockIdx.z;
    const int g = z >> 2, bsel = (z >> 1) & 1, ks = z & 1;
    const int tx = blockIdx.x;
    const u16* Ab;
    const u16* Bb;
    int lda, ldb, ldc, m0, n0;
    if (g == 0) {
        Ab = pkT + (size_t)ks * 2048;
        Bb = xkT + (size_t)bsel * 4096 + (size_t)ks * 2048;
        lda = 4096; ldb = 8192; ldc = 1024;
        m0 = (tx >> 3) << 7; n0 = (tx & 7) << 7;
    } else {
        Ab = xvT + (size_t)bsel * 4096 + (size_t)ks * 2048;
        Bb = pvT + (size_t)ks * 2048;
        lda = 8192; ldb = 4096; ldc = 2048;
        m0 = (tx >> 4) << 7; n0 = (tx & 15) << 7;
    }
    const int tid = threadIdx.x, wave = tid >> 6, lane = tid & 63;
    const int kg = lane >> 4, lr = lane & 15;
    const int wr = (wave >> 1) << 6, wc = (wave & 1) << 6;
    const int nT = 64;    // K2 = 2048
    f32x4 acc[4][4] = {};

#pragma unroll
    for (int i = 0; i < 2; i++) {
        int row = i * 64 + lane;
        GLD16(Ab + (size_t)(m0 + row) * lda + wave * 8, &lds[0][0][wave][i * 64][0]);
        GLD16(Bb + (size_t)(n0 + row) * ldb + wave * 8, &lds[0][1][wave][i * 64][0]);
    }
    for (int t = 0; t < nT; ++t) {
        const int cur = t & 1;
        if (t + 1 < nT) {
            const int nxt = cur ^ 1;
            const int koff = (t + 1) << 5;
#pragma unroll
            for (int i = 0; i < 2; i++) {
                int row = i * 64 + lane;
                GLD16(Ab + (size_t)(m0 + row) * lda + koff + wave * 8, &lds[nxt][0][wave][i * 64][0]);
                GLD16(Bb + (size_t)(n0 + row) * ldb + koff + wave * 8, &lds[nxt][1][wave][i * 64][0]);
            }
        }
        __syncthreads();
        bf16x8 af[4], bfv[4];
#pragma unroll
        for (int mi = 0; mi < 4; mi++)
            af[mi] = *(const bf16x8*)&lds[cur][0][kg][wr + mi * 16 + lr][0];
#pragma unroll
        for (int ni = 0; ni < 4; ni++)
            bfv[ni] = *(const bf16x8*)&lds[cur][1][kg][wc + ni * 16 + lr][0];
#pragma unroll
        for (int mi = 0; mi < 4; mi++)
#pragma unroll
            for (int ni = 0; ni < 4; ni++)
                acc[mi][ni] = __builtin_amdgcn_mfma_f32_16x16x32_bf16(af[mi], bfv[ni], acc[mi][ni], 0, 0, 0);
        __syncthreads();
    }

    u16* C = Cp + ((size_t)z << 21);
#pragma unroll
    for (int mi = 0; mi < 4; mi++)
#pragma unroll
        for (int ni = 0; ni < 4; ni++)
#pragma unroll
            for (int r = 0; r < 4; r++) {
                int gr = m0 + wr + mi * 16 + kg * 4 + r;
                int gc = n0 + wc + ni * 16 + lr;
                C[(size_t)gr * ldc + gc] = f2bf(acc[mi][ni][r]);
            }
}

// dst[d] = bf16( p[(2b)S + r] + p[(2b+1)S + r] ),  d = b*S + r, S = 2^21.
// With 4096 blocks: d in [0, 2^23) spans kbuf (slots 0-3 -> 2 batches) then
// vtb (slots 4-7), which are ADJACENT in the workspace (kbuf alloc = 8MB exact).
__global__ void combine_bf16(const u16* __restrict__ p, u16* __restrict__ dst) {
    int gid = blockIdx.x * 256 + threadIdx.x;
    size_t d = (size_t)gid * 8;
    size_t b = d >> 21, r = d & (((size_t)1 << 21) - 1);
    const ushort8 a = *(const ushort8*)(p + ((b * 2) << 21) + r);
    const ushort8 c = *(const ushort8*)(p + ((b * 2 + 1) << 21) + r);
    ushort8 o;
#pragma unroll
    for (int i = 0; i < 8; i++) o[i] = f2bf(bf2f(a[i]) + bf2f(c[i]));
    *(ushort8*)(dst + d) = o;
}

// ---------------- flash attention over compressed K/V (R17-green, frozen) -----
// Per wave: 16 q rows (q = nrow+lr), loop kp tiles of 32. 2 GLD16/thread;
// stage(nxt); barrier; process(cur); barrier. Mask word t+1 prefetched before
// the barrier. Math/xform/stores = R14/R17-proven.

__global__ __launch_bounds__(256) void attn_kernel(
    const u16* __restrict__ q, const u16* __restrict__ kb,
    const u16* __restrict__ vt, const unsigned* __restrict__ mw,
    u16* __restrict__ ao) {
    __shared__ __align__(16) u16 sK[2][8][32][8];   // [buf][dh8][kp][8] 4KB/buf
    __shared__ __align__(16) u16 sV[2][4][64][8];   // [buf][kp8][dh][8] 4KB/buf
    const int tid = threadIdx.x;
    const int wave = tid >> 6, lane = tid & 63, kg = lane >> 4, lr = lane & 15;
    const int b = blockIdx.x >> 4, h = blockIdx.x & 15;
    const int nrow = (blockIdx.y << 6) + wave * 16;

    const u16* qrow = q + (size_t)(b * 4096 + nrow + lr) * 1024 + h * 64 + kg * 8;
    const bf16x8 aq0 = *(const bf16x8*)qrow;
    const bf16x8 aq1 = *(const bf16x8*)(qrow + 32);
    const u16* kh = kb + (size_t)b * 2048 * 1024 + h * 64;
    const u16* vh = vt + ((size_t)b * 1024 + (size_t)h * 64) * 2048;
    const unsigned* mrow = mw + (size_t)(nrow + lr) * 64;

    // branch-free staging addresses (fixed per thread; only j0 varies)
    const u16* ksrc = kh + (size_t)(lane & 31) * 1024 + (wave * 2 + (lane >> 5)) * 8;
    const u16* vsrc = vh + (size_t)lane * 2048 + wave * 8;

    f32x4 o[4] = {};      // o[f][r] = O[q=lr][dh = f*16 + kg*4 + r] (unnormalized)
    float lsum = 0.0f;
    const bool low16 = (lane & 16) == 0;

    auto stage = [&](int bf, int j0) {
        GLD16(ksrc + (size_t)j0 * 1024, &sK[bf][wave * 2][0][0]);
        GLD16(vsrc + j0, &sV[bf][wave][0][0]);
    };

    auto process = [&](int cur, unsigned wd) {
        const bf16x8 k0a = *(const bf16x8*)&sK[cur][kg][lr][0];
        const bf16x8 k0b = *(const bf16x8*)&sK[cur][4 + kg][lr][0];
        const bf16x8 k1a = *(const bf16x8*)&sK[cur][kg][16 + lr][0];
        const bf16x8 k1b = *(const bf16x8*)&sK[cur][4 + kg][16 + lr][0];
        const bf16x8 v0 = *(const bf16x8*)&sV[cur][kg][lr][0];
        const bf16x8 v1 = *(const bf16x8*)&sV[cur][kg][16 + lr][0];
        const bf16x8 v2 = *(const bf16x8*)&sV[cur][kg][32 + lr][0];
        const bf16x8 v3 = *(const bf16x8*)&sV[cur][kg][48 + lr][0];

        f32x4 s0 = {0.f, 0.f, 0.f, 0.f}, s1 = {0.f, 0.f, 0.f, 0.f};
        s0 = __builtin_amdgcn_mfma_f32_16x16x32_bf16(k0a, aq0, s0, 0, 0, 0);
        s0 = __builtin_amdgcn_mfma_f32_16x16x32_bf16(k0b, aq1, s0, 0, 0, 0);
        s1 = __builtin_amdgcn_mfma_f32_16x16x32_bf16(k1a, aq0, s1, 0, 0, 0);
        s1 = __builtin_amdgcn_mfma_f32_16x16x32_bf16(k1b, aq1, s1, 0, 0, 0);
        const unsigned mb0 = wd >> (kg * 4);
        const unsigned mb1 = wd >> (16 + kg * 4);
        // p = exp2(s * (0.125*log2e)); masked -> 0
        const float C = 0.18033688f;
        float p0[4], p1[4];
#pragma unroll
        for (int r = 0; r < 4; r++) {
            float t0 = ((mb0 >> r) & 1u) ? -1.0e30f : s0[r] * C;
            float t1 = ((mb1 >> r) & 1u) ? -1.0e30f : s1[r] * C;
            p0[r] = fexp2(t0);
            p1[r] = fexp2(t1);
            lsum += p0[r] + p1[r];
        }
        // pack to bf16 pairs: c* hold kp kg*4+{01,23}, d* hold kp 16+kg*4+{01,23}
        unsigned X0 = cvt_pk_bf16(p0[0], p0[1]);
        unsigned X1 = cvt_pk_bf16(p0[2], p0[3]);
        unsigned Y0 = cvt_pk_bf16(p1[0], p1[1]);
        unsigned Y1 = cvt_pk_bf16(p1[2], p1[3]);
        // lane-transpose P^T -> B-frag (lane needs kp slice kg*8..kg*8+7 for q=lr)
        asm volatile("v_permlane32_swap_b32 %0, %1" : "+v"(X0), "+v"(Y0));
        asm volatile("v_permlane32_swap_b32 %0, %1" : "+v"(X1), "+v"(Y1));
        unsigned sX0 = (unsigned)__shfl_xor((int)X0, 16);
        unsigned sY0 = (unsigned)__shfl_xor((int)Y0, 16);
        unsigned sX1 = (unsigned)__shfl_xor((int)X1, 16);
        unsigned sY1 = (unsigned)__shfl_xor((int)Y1, 16);
        uint4v wv;
        wv[0] = low16 ? X0 : sY0;
        wv[1] = low16 ? X1 : sY1;
        wv[2] = low16 ? sX0 : Y0;
        wv[3] = low16 ? sX1 : Y1;
        bf16x8 W = __builtin_bit_cast(bf16x8, wv);
        o[0] = __builtin_amdgcn_mfma_f32_16x16x32_bf16(v0, W, o[0], 0, 0, 0);
        o[1] = __builtin_amdgcn_mfma_f32_16x16x32_bf16(v1, W, o[1], 0, 0, 0);
        o[2] = __builtin_amdgcn_mfma_f32_16x16x32_bf16(v2, W, o[2], 0, 0, 0);
        o[3] = __builtin_amdgcn_mfma_f32_16x16x32_bf16(v3, W, o[3], 0, 0, 0);
    };

    stage(0, 0);
    unsigned wdc = mrow[0];
    for (int t = 0; t < 64; ++t) {
        const int cur = t & 1;
        if (t < 63) stage(cur ^ 1, (t + 1) * 32);
        unsigned wdn = (t < 63) ? mrow[t + 1] : 0u;   // prefetch next mask word
        __syncthreads();   // drains vmcnt -> buf[cur] ready (and wdn)
        process(cur, wdc);
        wdc = wdn;
        __syncthreads();   // all reads of buf[cur] done before re-stage
    }

    lsum += __shfl_xor(lsum, 16);
    lsum += __shfl_xor(lsum, 32);
    const float inv = 1.0f / lsum;

    u16* orow = ao + (size_t)(b * 4096 + nrow + lr) * 1024 + h * 64 + kg * 4;
#pragma unroll
    for (int f = 0; f < 4; f++) {
        uint2v st;
        st[0] = cvt_pk_bf16(o[f][0] * inv, o[f][1] * inv);
        st[1] = cvt_pk_bf16(o[f][2] * inv, o[f][3] * inv);
        *(uint2v*)(orow + f * 16) = st;
    }
}

// ---------------- launcher ----------------

extern "C" void kernel_launch(void* const* d_in, const int* in_sizes, int n_in,
                              void* d_out, int out_size, void* d_ws, size_t ws_size,
                              hipStream_t stream) {
    const float* x    = (const float*)d_in[0];
    const float* mask = (const float*)d_in[1];
    const float* Wq   = (const float*)d_in[2];
    const float* Wk   = (const float*)d_in[3];
    const float* Wv   = (const float*)d_in[4];
    const float* Wo   = (const float*)d_in[5];
    const float* bo   = (const float*)d_in[6];
    const float* pk   = (const float*)d_in[7];
    const float* pv   = (const float*)d_in[8];
    float* out = (float*)d_out;

    char* w = (char*)d_ws;
    auto alloc = [&](size_t bytes) { void* p = w; w += (bytes + 255) & ~(size_t)255; return p; };
    u16* xb   = (u16*)alloc((size_t)8192 * 1024 * 2);
    u16* qb   = (u16*)alloc((size_t)8192 * 1024 * 2);
    u16* xkT  = (u16*)alloc((size_t)1024 * 8192 * 2);   // [xkT|xvT] contiguous:
    u16* xvT  = (u16*)alloc((size_t)1024 * 8192 * 2);   // fused M=2048 GEMM output
    u16* WqT  = (u16*)alloc((size_t)1024 * 1024 * 2);
    u16* WkT  = (u16*)alloc((size_t)1024 * 1024 * 2);   // [WkT|WvT] contiguous:
    u16* WvT  = (u16*)alloc((size_t)1024 * 1024 * 2);   // fused GEMM A-operand
    u16* WoT  = (u16*)alloc((size_t)1024 * 1024 * 2);
    u16* pkT  = (u16*)alloc((size_t)2048 * 4096 * 2);
    u16* pvT  = (u16*)alloc((size_t)2048 * 4096 * 2);
    u16* kbuf = (u16*)alloc((size_t)2 * 2048 * 1024 * 2);   // 8MB exact -> vtb adjacent
    u16* vtb  = (u16*)alloc((size_t)2 * 1024 * 2048 * 2);
    unsigned* mw = (unsigned*)alloc((size_t)4096 * 64 * 4);
    (void)alloc((size_t)128 * 1024);   // guard pad
    u16* ao   = xb;          // alias: xb dead after q-proj; attn writes after that
    u16* pbuf = (u16*)out;   // d_out as scratch: 8 x 2^21 bf16 = 32MB <= 33.5MB;
                             // fully overwritten by the final f32 GEMM
    (void)xvT;

    convert_bf16<<<4096, 256, 0, stream>>>(x, xb);
    transpose_convert<<<dim3(16, 16), 256, 0, stream>>>(Wq, WqT, 1024, 1024);
    transpose_convert<<<dim3(16, 16), 256, 0, stream>>>(Wk, WkT, 1024, 1024);
    transpose_convert<<<dim3(16, 16), 256, 0, stream>>>(Wv, WvT, 1024, 1024);
    transpose_convert<<<dim3(16, 16), 256, 0, stream>>>(Wo, WoT, 1024, 1024);
    transpose_convert<<<dim3(32, 64), 256, 0, stream>>>(pk, pkT, 4096, 2048);
    transpose_convert<<<dim3(32, 64), 256, 0, stream>>>(pv, pvT, 4096, 2048);
    mask_pack<<<32768, 256, 0, stream>>>(mask, mw);

    // fused [xkT|xvT] = [WkT|WvT](M=2048) x B(xb) : [2048,8192], one launch
    gemm_nt<true, false><<<dim3(64, 16, 1), 256, 0, stream>>>(WkT, 1024, 0, xb, 1024, 0, xkT, 8192, 0, nullptr, 1024);

    // both compress GEMMs, split-K x2, one 1024-block launch -> d_out partials
    gemm_nt_splitk2<<<dim3(128, 1, 8), 256, 0, stream>>>(pkT, xkT, xvT, pvT, pbuf);
    // one combine: slots 0-3 -> kbuf, slots 4-7 -> vtb (adjacent region)
    combine_bf16<<<4096, 256, 0, stream>>>(pbuf, kbuf);

    // q = x @ Wq
    gemm_nt<true, false><<<dim3(8, 64, 1), 256, 0, stream>>>(xb, 1024, 0, WqT, 1024, 0, qb, 1024, 0, nullptr, 1024);

    // grid (bh, qchunk): consecutive blocks differ in bh -> XCD = bh%8 (L2 locality)
    attn_kernel<<<dim3(32, 64), 256, 0, stream>>>(qb, kbuf, vtb, mw, ao);

    // out = ao @ Wo + bo (f32 out; overwrites the pbuf scratch completely)
    gemm_nt<false, true><<<dim3(8, 64, 1), 256, 0, stream>>>(ao, 1024, 0, WoT, 1024, 0, out, 1024, 0, bo, 1024);
}

// Round 20
// 549.074 us; speedup vs baseline: 1.0399x; 1.0275x over previous
//
#include <hip/hip_runtime.h>
#include <stdint.h>

using u16 = unsigned short;
typedef __bf16 bf16x8 __attribute__((ext_vector_type(8)));
typedef float f32x4 __attribute__((ext_vector_type(4)));
typedef u16 ushort8 __attribute__((ext_vector_type(8)));
typedef unsigned uint4v __attribute__((ext_vector_type(4)));
typedef unsigned uint2v __attribute__((ext_vector_type(2)));

// ===== session ledger (do not violate) =====
// attn_kernel on this toolchain:
//  - NO __builtin_amdgcn_s_setprio around MFMA (R5/R7: absmax 2.6e28)
//  - NO __launch_bounds__ second arg (R4/R11/R12: three bodies, all corrupt)
//  - NO v_permlane16_swap (R10: wrong lane routing)
//  - NO global_load_lds under wave-divergent branches (R2/R3)
//  - NO single-barrier multi-buffer pipelines (R15: 0.359)
//  - NO extra GLD16 per barrier interval in attn (R16: 0.116)
//  - 2-q-frag/wave: green but SLOWER (R18: occupancy 48->23%, +18us)
// launcher:
//  - NO co-scheduling both compress GEMMs in one launch (R19: 64MB L2
//    working set thrash, +15.6us). Separate launches, pbuf=qb.
// => This file is the R17-green champion (548.6us) restored exactly.
// ===========================================

__device__ __forceinline__ u16 f2bf(float f) {
    unsigned u = __builtin_bit_cast(unsigned, f);
    return (u16)((u + 0x7fffu + ((u >> 16) & 1u)) >> 16);
}

__device__ __forceinline__ float bf2f(u16 v) {
    unsigned u = (unsigned)v << 16;
    return __builtin_bit_cast(float, u);
}

__device__ __forceinline__ float fexp2(float x) {
#if __has_builtin(__builtin_amdgcn_exp2f)
    return __builtin_amdgcn_exp2f(x);
#else
    return exp2f(x);
#endif
}

__device__ __forceinline__ unsigned cvt_pk_bf16(float lo, float hi) {
    unsigned r;
    asm("v_cvt_pk_bf16_f32 %0, %1, %2" : "=v"(r) : "v"(lo), "v"(hi));
    return r;
}

// global->LDS direct copy, 16B per lane. LDS dest is wave-uniform base + lane*16.
#define GLD16(gptr, lptr) __builtin_amdgcn_global_load_lds( \
    (const __attribute__((address_space(1))) void*)(unsigned long long)(gptr), \
    (__attribute__((address_space(3))) void*)(unsigned)(unsigned long long)(lptr), 16, 0, 0)

// ---------------- conversion kernels ----------------

__global__ void convert_bf16(const float* __restrict__ in, u16* __restrict__ out) {
    int gid = blockIdx.x * 256 + threadIdx.x;      // 8 f32 per thread
    const float4* in4 = (const float4*)in;
    float4 a = in4[2 * gid], b = in4[2 * gid + 1];
    ushort8 o;
    o[0] = f2bf(a.x); o[1] = f2bf(a.y); o[2] = f2bf(a.z); o[3] = f2bf(a.w);
    o[4] = f2bf(b.x); o[5] = f2bf(b.y); o[6] = f2bf(b.z); o[7] = f2bf(b.w);
    *(ushort8*)(out + (size_t)gid * 8) = o;
}

// out[C][R] = bf16(in[R][C])  -- 64x64 LDS tile transpose
__global__ void transpose_convert(const float* __restrict__ in, u16* __restrict__ out,
                                  int R, int C) {
    __shared__ u16 sT[64][65];
    const int c0 = blockIdx.x << 6, r0 = blockIdx.y << 6;
    const int tid = threadIdx.x;
#pragma unroll
    for (int rep = 0; rep < 16; rep++) {
        int idx = rep * 256 + tid;
        int r = idx >> 6, c = idx & 63;
        sT[c][r] = f2bf(in[(size_t)(r0 + r) * C + c0 + c]);
    }
    __syncthreads();
#pragma unroll
    for (int rep = 0; rep < 16; rep++) {
        int idx = rep * 256 + tid;
        int r = idx >> 6, c = idx & 63;
        out[(size_t)(c0 + r) * R + r0 + c] = sT[r][c];
    }
}

// maskbits[i][w] bit (j&31) = (mask[i][2j+1] != 0), j = resized col index
__global__ void mask_pack(const float* __restrict__ mask, unsigned* __restrict__ mw) {
    int gid = blockIdx.x * 256 + threadIdx.x;      // 4096*2048 threads
    int i = gid >> 11, j = gid & 2047;
    float v = mask[(size_t)i * 4096 + 2 * j + 1];
    unsigned long long b = __ballot(v != 0.0f);
    int lane = threadIdx.x & 63;
    if (lane == 0)       mw[(size_t)i * 64 + (j >> 5)] = (unsigned)b;
    else if (lane == 32) mw[(size_t)i * 64 + (j >> 5)] = (unsigned)(b >> 32);
}

// ---------------- NT GEMM: C[i][j] = sum_k A[i][k]*B[j][k] ----------------
// A [M][K] row-major bf16, B [N][K] row-major bf16. 128x128 tile, BK=32, dbuf LDS.
// grid = (N/128, M/128, batches)

template <bool OUT_BF16, bool ADD_BIAS>
__global__ __launch_bounds__(256) void gemm_nt(
    const u16* __restrict__ A, int lda, long long sA,
    const u16* __restrict__ B, int ldb, long long sB,
    void* __restrict__ Cp, int ldc, long long sC,
    const float* __restrict__ bias, int K) {
    __shared__ __align__(16) u16 lds[2][2][4][128][8];   // [buf][mat][kblk][row][8] = 32KB
    const int bz = blockIdx.z;
    const u16* Ab = A + (size_t)sA * bz;
    const u16* Bb = B + (size_t)sB * bz;
    const int m0 = blockIdx.y << 7, n0 = blockIdx.x << 7;
    const int tid = threadIdx.x, wave = tid >> 6, lane = tid & 63;
    const int kg = lane >> 4, lr = lane & 15;
    const int wr = (wave >> 1) << 6, wc = (wave & 1) << 6;
    const int nT = K >> 5;
    f32x4 acc[4][4] = {};

    // prologue: stage tile 0 into buf 0. wave stages kblk==wave, rows i*64+lane.
#pragma unroll
    for (int i = 0; i < 2; i++) {
        int row = i * 64 + lane;
        GLD16(Ab + (size_t)(m0 + row) * lda + wave * 8, &lds[0][0][wave][i * 64][0]);
        GLD16(Bb + (size_t)(n0 + row) * ldb + wave * 8, &lds[0][1][wave][i * 64][0]);
    }
    for (int t = 0; t < nT; ++t) {
        const int cur = t & 1;
        if (t + 1 < nT) {
            const int nxt = cur ^ 1;
            const int koff = (t + 1) << 5;
#pragma unroll
            for (int i = 0; i < 2; i++) {
                int row = i * 64 + lane;
                GLD16(Ab + (size_t)(m0 + row) * lda + koff + wave * 8, &lds[nxt][0][wave][i * 64][0]);
                GLD16(Bb + (size_t)(n0 + row) * ldb + koff + wave * 8, &lds[nxt][1][wave][i * 64][0]);
            }
        }
        __syncthreads();   // drains vmcnt -> buf[cur] ready
        bf16x8 af[4], bfv[4];
#pragma unroll
        for (int mi = 0; mi < 4; mi++)
            af[mi] = *(const bf16x8*)&lds[cur][0][kg][wr + mi * 16 + lr][0];
#pragma unroll
        for (int ni = 0; ni < 4; ni++)
            bfv[ni] = *(const bf16x8*)&lds[cur][1][kg][wc + ni * 16 + lr][0];
#pragma unroll
        for (int mi = 0; mi < 4; mi++)
#pragma unroll
            for (int ni = 0; ni < 4; ni++)
                acc[mi][ni] = __builtin_amdgcn_mfma_f32_16x16x32_bf16(af[mi], bfv[ni], acc[mi][ni], 0, 0, 0);
        __syncthreads();   // all reads of buf[cur] done before it is re-staged
    }

    if constexpr (OUT_BF16) {
        u16* C = (u16*)Cp + (size_t)sC * bz;
#pragma unroll
        for (int mi = 0; mi < 4; mi++)
#pragma unroll
            for (int ni = 0; ni < 4; ni++)
#pragma unroll
                for (int r = 0; r < 4; r++) {
                    int gr = m0 + wr + mi * 16 + kg * 4 + r;
                    int gc = n0 + wc + ni * 16 + lr;
                    C[(size_t)gr * ldc + gc] = f2bf(acc[mi][ni][r]);
                }
    } else {
        float* C = (float*)Cp + (size_t)sC * bz;
#pragma unroll
        for (int mi = 0; mi < 4; mi++)
#pragma unroll
            for (int ni = 0; ni < 4; ni++)
#pragma unroll
                for (int r = 0; r < 4; r++) {
                    int gr = m0 + wr + mi * 16 + kg * 4 + r;
                    int gc = n0 + wc + ni * 16 + lr;
                    float v = acc[mi][ni][r];
                    if constexpr (ADD_BIAS) v += bias[gc];
                    C[(size_t)gr * ldc + gc] = v;
                }
    }
}

// ---- split-K variant: bz in [0,4) = (bsel = bz>>1, ks = bz&1). bf16 partials.
// Cpart[bz][i][j] = sum_{k in half ks} A[bsel-slice][i][k] * B[bsel-slice][j][k]
__global__ __launch_bounds__(256) void gemm_nt_splitk(
    const u16* __restrict__ A, int lda, long long sAb,
    const u16* __restrict__ B, int ldb, long long sBb,
    u16* __restrict__ Cp, int ldc, long long sC, int K2) {
    __shared__ __align__(16) u16 lds[2][2][4][128][8];
    const int bz = blockIdx.z, bsel = bz >> 1, ks = bz & 1;
    const u16* Ab = A + (size_t)sAb * bsel + (size_t)ks * K2;
    const u16* Bb = B + (size_t)sBb * bsel + (size_t)ks * K2;
    const int m0 = blockIdx.y << 7, n0 = blockIdx.x << 7;
    const int tid = threadIdx.x, wave = tid >> 6, lane = tid & 63;
    const int kg = lane >> 4, lr = lane & 15;
    const int wr = (wave >> 1) << 6, wc = (wave & 1) << 6;
    const int nT = K2 >> 5;
    f32x4 acc[4][4] = {};

#pragma unroll
    for (int i = 0; i < 2; i++) {
        int row = i * 64 + lane;
        GLD16(Ab + (size_t)(m0 + row) * lda + wave * 8, &lds[0][0][wave][i * 64][0]);
        GLD16(Bb + (size_t)(n0 + row) * ldb + wave * 8, &lds[0][1][wave][i * 64][0]);
    }
    for (int t = 0; t < nT; ++t) {
        const int cur = t & 1;
        if (t + 1 < nT) {
            const int nxt = cur ^ 1;
            const int koff = (t + 1) << 5;
#pragma unroll
            for (int i = 0; i < 2; i++) {
                int row = i * 64 + lane;
                GLD16(Ab + (size_t)(m0 + row) * lda + koff + wave * 8, &lds[nxt][0][wave][i * 64][0]);
                GLD16(Bb + (size_t)(n0 + row) * ldb + koff + wave * 8, &lds[nxt][1][wave][i * 64][0]);
            }
        }
        __syncthreads();
        bf16x8 af[4], bfv[4];
#pragma unroll
        for (int mi = 0; mi < 4; mi++)
            af[mi] = *(const bf16x8*)&lds[cur][0][kg][wr + mi * 16 + lr][0];
#pragma unroll
        for (int ni = 0; ni < 4; ni++)
            bfv[ni] = *(const bf16x8*)&lds[cur][1][kg][wc + ni * 16 + lr][0];
#pragma unroll
        for (int mi = 0; mi < 4; mi++)
#pragma unroll
            for (int ni = 0; ni < 4; ni++)
                acc[mi][ni] = __builtin_amdgcn_mfma_f32_16x16x32_bf16(af[mi], bfv[ni], acc[mi][ni], 0, 0, 0);
        __syncthreads();
    }

    u16* C = Cp + (size_t)sC * bz;
#pragma unroll
    for (int mi = 0; mi < 4; mi++)
#pragma unroll
        for (int ni = 0; ni < 4; ni++)
#pragma unroll
            for (int r = 0; r < 4; r++) {
                int gr = m0 + wr + mi * 16 + kg * 4 + r;
                int gc = n0 + wc + ni * 16 + lr;
                C[(size_t)gr * ldc + gc] = f2bf(acc[mi][ni][r]);
            }
}

// dst[d] = bf16( p[(2b)S + r] + p[(2b+1)S + r] ),  d = b*S + r, S = 2^21
__global__ void combine_bf16(const u16* __restrict__ p, u16* __restrict__ dst) {
    int gid = blockIdx.x * 256 + threadIdx.x;   // 524288 threads, 8 elems each
    size_t d = (size_t)gid * 8;
    size_t b = d >> 21, r = d & (((size_t)1 << 21) - 1);
    const ushort8 a = *(const ushort8*)(p + ((b * 2) << 21) + r);
    const ushort8 c = *(const ushort8*)(p + ((b * 2 + 1) << 21) + r);
    ushort8 o;
#pragma unroll
    for (int i = 0; i < 8; i++) o[i] = f2bf(bf2f(a[i]) + bf2f(c[i]));
    *(ushort8*)(dst + d) = o;
}

// ---------------- flash attention over compressed K/V (R17-green, frozen) -----
// Per wave: 16 q rows (q = nrow+lr), loop kp tiles of 32. 2 GLD16/thread;
// stage(nxt); barrier; process(cur); barrier. Mask word t+1 prefetched before
// the barrier. Math/xform/stores = R14/R17-proven.

__global__ __launch_bounds__(256) void attn_kernel(
    const u16* __restrict__ q, const u16* __restrict__ kb,
    const u16* __restrict__ vt, const unsigned* __restrict__ mw,
    u16* __restrict__ ao) {
    __shared__ __align__(16) u16 sK[2][8][32][8];   // [buf][dh8][kp][8] 4KB/buf
    __shared__ __align__(16) u16 sV[2][4][64][8];   // [buf][kp8][dh][8] 4KB/buf
    const int tid = threadIdx.x;
    const int wave = tid >> 6, lane = tid & 63, kg = lane >> 4, lr = lane & 15;
    const int b = blockIdx.x >> 4, h = blockIdx.x & 15;
    const int nrow = (blockIdx.y << 6) + wave * 16;

    const u16* qrow = q + (size_t)(b * 4096 + nrow + lr) * 1024 + h * 64 + kg * 8;
    const bf16x8 aq0 = *(const bf16x8*)qrow;
    const bf16x8 aq1 = *(const bf16x8*)(qrow + 32);
    const u16* kh = kb + (size_t)b * 2048 * 1024 + h * 64;
    const u16* vh = vt + ((size_t)b * 1024 + (size_t)h * 64) * 2048;
    const unsigned* mrow = mw + (size_t)(nrow + lr) * 64;

    // branch-free staging addresses (fixed per thread; only j0 varies)
    const u16* ksrc = kh + (size_t)(lane & 31) * 1024 + (wave * 2 + (lane >> 5)) * 8;
    const u16* vsrc = vh + (size_t)lane * 2048 + wave * 8;

    f32x4 o[4] = {};      // o[f][r] = O[q=lr][dh = f*16 + kg*4 + r] (unnormalized)
    float lsum = 0.0f;
    const bool low16 = (lane & 16) == 0;

    auto stage = [&](int bf, int j0) {
        GLD16(ksrc + (size_t)j0 * 1024, &sK[bf][wave * 2][0][0]);
        GLD16(vsrc + j0, &sV[bf][wave][0][0]);
    };

    auto process = [&](int cur, unsigned wd) {
        const bf16x8 k0a = *(const bf16x8*)&sK[cur][kg][lr][0];
        const bf16x8 k0b = *(const bf16x8*)&sK[cur][4 + kg][lr][0];
        const bf16x8 k1a = *(const bf16x8*)&sK[cur][kg][16 + lr][0];
        const bf16x8 k1b = *(const bf16x8*)&sK[cur][4 + kg][16 + lr][0];
        const bf16x8 v0 = *(const bf16x8*)&sV[cur][kg][lr][0];
        const bf16x8 v1 = *(const bf16x8*)&sV[cur][kg][16 + lr][0];
        const bf16x8 v2 = *(const bf16x8*)&sV[cur][kg][32 + lr][0];
        const bf16x8 v3 = *(const bf16x8*)&sV[cur][kg][48 + lr][0];

        f32x4 s0 = {0.f, 0.f, 0.f, 0.f}, s1 = {0.f, 0.f, 0.f, 0.f};
        s0 = __builtin_amdgcn_mfma_f32_16x16x32_bf16(k0a, aq0, s0, 0, 0, 0);
        s0 = __builtin_amdgcn_mfma_f32_16x16x32_bf16(k0b, aq1, s0, 0, 0, 0);
        s1 = __builtin_amdgcn_mfma_f32_16x16x32_bf16(k1a, aq0, s1, 0, 0, 0);
        s1 = __builtin_amdgcn_mfma_f32_16x16x32_bf16(k1b, aq1, s1, 0, 0, 0);
        const unsigned mb0 = wd >> (kg * 4);
        const unsigned mb1 = wd >> (16 + kg * 4);
        // p = exp2(s * (0.125*log2e)); masked -> 0
        const float C = 0.18033688f;
        float p0[4], p1[4];
#pragma unroll
        for (int r = 0; r < 4; r++) {
            float t0 = ((mb0 >> r) & 1u) ? -1.0e30f : s0[r] * C;
            float t1 = ((mb1 >> r) & 1u) ? -1.0e30f : s1[r] * C;
            p0[r] = fexp2(t0);
            p1[r] = fexp2(t1);
            lsum += p0[r] + p1[r];
        }
        // pack to bf16 pairs: c* hold kp kg*4+{01,23}, d* hold kp 16+kg*4+{01,23}
        unsigned X0 = cvt_pk_bf16(p0[0], p0[1]);
        unsigned X1 = cvt_pk_bf16(p0[2], p0[3]);
        unsigned Y0 = cvt_pk_bf16(p1[0], p1[1]);
        unsigned Y1 = cvt_pk_bf16(p1[2], p1[3]);
        // lane-transpose P^T -> B-frag (lane needs kp slice kg*8..kg*8+7 for q=lr)
        asm volatile("v_permlane32_swap_b32 %0, %1" : "+v"(X0), "+v"(Y0));
        asm volatile("v_permlane32_swap_b32 %0, %1" : "+v"(X1), "+v"(Y1));
        unsigned sX0 = (unsigned)__shfl_xor((int)X0, 16);
        unsigned sY0 = (unsigned)__shfl_xor((int)Y0, 16);
        unsigned sX1 = (unsigned)__shfl_xor((int)X1, 16);
        unsigned sY1 = (unsigned)__shfl_xor((int)Y1, 16);
        uint4v wv;
        wv[0] = low16 ? X0 : sY0;
        wv[1] = low16 ? X1 : sY1;
        wv[2] = low16 ? sX0 : Y0;
        wv[3] = low16 ? sX1 : Y1;
        bf16x8 W = __builtin_bit_cast(bf16x8, wv);
        o[0] = __builtin_amdgcn_mfma_f32_16x16x32_bf16(v0, W, o[0], 0, 0, 0);
        o[1] = __builtin_amdgcn_mfma_f32_16x16x32_bf16(v1, W, o[1], 0, 0, 0);
        o[2] = __builtin_amdgcn_mfma_f32_16x16x32_bf16(v2, W, o[2], 0, 0, 0);
        o[3] = __builtin_amdgcn_mfma_f32_16x16x32_bf16(v3, W, o[3], 0, 0, 0);
    };

    stage(0, 0);
    unsigned wdc = mrow[0];
    for (int t = 0; t < 64; ++t) {
        const int cur = t & 1;
        if (t < 63) stage(cur ^ 1, (t + 1) * 32);
        unsigned wdn = (t < 63) ? mrow[t + 1] : 0u;   // prefetch next mask word
        __syncthreads();   // drains vmcnt -> buf[cur] ready (and wdn)
        process(cur, wdc);
        wdc = wdn;
        __syncthreads();   // all reads of buf[cur] done before re-stage
    }

    lsum += __shfl_xor(lsum, 16);
    lsum += __shfl_xor(lsum, 32);
    const float inv = 1.0f / lsum;

    u16* orow = ao + (size_t)(b * 4096 + nrow + lr) * 1024 + h * 64 + kg * 4;
#pragma unroll
    for (int f = 0; f < 4; f++) {
        uint2v st;
        st[0] = cvt_pk_bf16(o[f][0] * inv, o[f][1] * inv);
        st[1] = cvt_pk_bf16(o[f][2] * inv, o[f][3] * inv);
        *(uint2v*)(orow + f * 16) = st;
    }
}

// ---------------- launcher ----------------

extern "C" void kernel_launch(void* const* d_in, const int* in_sizes, int n_in,
                              void* d_out, int out_size, void* d_ws, size_t ws_size,
                              hipStream_t stream) {
    const float* x    = (const float*)d_in[0];
    const float* mask = (const float*)d_in[1];
    const float* Wq   = (const float*)d_in[2];
    const float* Wk   = (const float*)d_in[3];
    const float* Wv   = (const float*)d_in[4];
    const float* Wo   = (const float*)d_in[5];
    const float* bo   = (const float*)d_in[6];
    const float* pk   = (const float*)d_in[7];
    const float* pv   = (const float*)d_in[8];
    float* out = (float*)d_out;

    char* w = (char*)d_ws;
    auto alloc = [&](size_t bytes) { void* p = w; w += (bytes + 255) & ~(size_t)255; return p; };
    u16* xb   = (u16*)alloc((size_t)8192 * 1024 * 2);
    u16* qb   = (u16*)alloc((size_t)8192 * 1024 * 2);
    u16* xkT  = (u16*)alloc((size_t)1024 * 8192 * 2);   // [xkT|xvT] contiguous:
    u16* xvT  = (u16*)alloc((size_t)1024 * 8192 * 2);   // fused M=2048 GEMM output
    u16* WqT  = (u16*)alloc((size_t)1024 * 1024 * 2);
    u16* WkT  = (u16*)alloc((size_t)1024 * 1024 * 2);   // [WkT|WvT] contiguous:
    u16* WvT  = (u16*)alloc((size_t)1024 * 1024 * 2);   // fused GEMM A-operand
    u16* WoT  = (u16*)alloc((size_t)1024 * 1024 * 2);
    u16* pkT  = (u16*)alloc((size_t)2048 * 4096 * 2);
    u16* pvT  = (u16*)alloc((size_t)2048 * 4096 * 2);
    u16* kbuf = (u16*)alloc((size_t)2 * 2048 * 1024 * 2);
    u16* vtb  = (u16*)alloc((size_t)2 * 1024 * 2048 * 2);
    unsigned* mw = (unsigned*)alloc((size_t)4096 * 64 * 4);
    (void)alloc((size_t)128 * 1024);   // guard pad
    u16* ao   = xb;   // alias: xb dead after q-proj; attention writes after that
    u16* pbuf = qb;   // alias: 4 x 2048x1024 bf16 partials = 16MB, dead before q-proj
    (void)xvT;

    convert_bf16<<<4096, 256, 0, stream>>>(x, xb);
    transpose_convert<<<dim3(16, 16), 256, 0, stream>>>(Wq, WqT, 1024, 1024);
    transpose_convert<<<dim3(16, 16), 256, 0, stream>>>(Wk, WkT, 1024, 1024);
    transpose_convert<<<dim3(16, 16), 256, 0, stream>>>(Wv, WvT, 1024, 1024);
    transpose_convert<<<dim3(16, 16), 256, 0, stream>>>(Wo, WoT, 1024, 1024);
    transpose_convert<<<dim3(32, 64), 256, 0, stream>>>(pk, pkT, 4096, 2048);
    transpose_convert<<<dim3(32, 64), 256, 0, stream>>>(pv, pvT, 4096, 2048);
    mask_pack<<<32768, 256, 0, stream>>>(mask, mw);

    // fused [xkT|xvT] = [WkT|WvT](M=2048) x B(xb) : [2048,8192], one launch
    gemm_nt<true, false><<<dim3(64, 16, 1), 256, 0, stream>>>(WkT, 1024, 0, xb, 1024, 0, xkT, 8192, 0, nullptr, 1024);

    // k[b] = proj_k^T @ xk[b] : split-K x2 -> bf16 partials -> combine
    gemm_nt_splitk<<<dim3(8, 16, 4), 256, 0, stream>>>(pkT, 4096, 0, xkT, 8192, 4096,
                                                       pbuf, 1024, (long long)1 << 21, 2048);
    combine_bf16<<<2048, 256, 0, stream>>>(pbuf, kbuf);
    // vT[b] = xv[b]^T @ proj_v : split-K x2
    gemm_nt_splitk<<<dim3(16, 8, 4), 256, 0, stream>>>(xvT, 8192, 4096, pvT, 4096, 0,
                                                       pbuf, 2048, (long long)1 << 21, 2048);
    combine_bf16<<<2048, 256, 0, stream>>>(pbuf, vtb);

    // q = x @ Wq (runs AFTER combines: qb overlays pbuf)
    gemm_nt<true, false><<<dim3(8, 64, 1), 256, 0, stream>>>(xb, 1024, 0, WqT, 1024, 0, qb, 1024, 0, nullptr, 1024);

    // grid (bh, qchunk): consecutive blocks differ in bh -> XCD = bh%8 (L2 locality)
    attn_kernel<<<dim3(32, 64), 256, 0, stream>>>(qb, kbuf, vtb, mw, ao);

    // out = ao @ Wo + bo (f32 out; fully overwritten each call)
    gemm_nt<false, true><<<dim3(8, 64, 1), 256, 0, stream>>>(ao, 1024, 0, WoT, 1024, 0, out, 1024, 0, bo, 1024);
}

// Round 21
// 539.466 us; speedup vs baseline: 1.0585x; 1.0178x over previous
//
#include <hip/hip_runtime.h>
#include <stdint.h>

using u16 = unsigned short;
typedef __bf16 bf16x8 __attribute__((ext_vector_type(8)));
typedef float f32x4 __attribute__((ext_vector_type(4)));
typedef u16 ushort8 __attribute__((ext_vector_type(8)));
typedef unsigned uint4v __attribute__((ext_vector_type(4)));
typedef unsigned uint2v __attribute__((ext_vector_type(2)));

// ===== session ledger (do not violate) =====
// attn_kernel on this toolchain:
//  - NO __builtin_amdgcn_s_setprio around MFMA (R5/R7: absmax 2.6e28)
//  - NO __launch_bounds__ second arg (R4/R11/R12: three bodies, all corrupt)
//  - NO v_permlane16_swap (R10: wrong lane routing)
//  - NO global_load_lds under wave-divergent branches (R2/R3)
//  - NO single-barrier multi-buffer pipelines (R15: 0.359)
//  - NO extra GLD16 per barrier interval in attn (R16: 0.116)
//  - 2-q-frag/wave: green but SLOWER (R18: occupancy 48->23%, +18us)
// launcher:
//  - NO co-scheduling both compress GEMMs in one launch (R19: +15.6us)
// R21 delta: z-batched transposes ONLY (block-uniform pointer select,
// same proven body) to cut preamble launches 8 -> 4.
// ===========================================

__device__ __forceinline__ u16 f2bf(float f) {
    unsigned u = __builtin_bit_cast(unsigned, f);
    return (u16)((u + 0x7fffu + ((u >> 16) & 1u)) >> 16);
}

__device__ __forceinline__ float bf2f(u16 v) {
    unsigned u = (unsigned)v << 16;
    return __builtin_bit_cast(float, u);
}

__device__ __forceinline__ float fexp2(float x) {
#if __has_builtin(__builtin_amdgcn_exp2f)
    return __builtin_amdgcn_exp2f(x);
#else
    return exp2f(x);
#endif
}

__device__ __forceinline__ unsigned cvt_pk_bf16(float lo, float hi) {
    unsigned r;
    asm("v_cvt_pk_bf16_f32 %0, %1, %2" : "=v"(r) : "v"(lo), "v"(hi));
    return r;
}

// global->LDS direct copy, 16B per lane. LDS dest is wave-uniform base + lane*16.
#define GLD16(gptr, lptr) __builtin_amdgcn_global_load_lds( \
    (const __attribute__((address_space(1))) void*)(unsigned long long)(gptr), \
    (__attribute__((address_space(3))) void*)(unsigned)(unsigned long long)(lptr), 16, 0, 0)

// ---------------- conversion kernels ----------------

__global__ void convert_bf16(const float* __restrict__ in, u16* __restrict__ out) {
    int gid = blockIdx.x * 256 + threadIdx.x;      // 8 f32 per thread
    const float4* in4 = (const float4*)in;
    float4 a = in4[2 * gid], b = in4[2 * gid + 1];
    ushort8 o;
    o[0] = f2bf(a.x); o[1] = f2bf(a.y); o[2] = f2bf(a.z); o[3] = f2bf(a.w);
    o[4] = f2bf(b.x); o[5] = f2bf(b.y); o[6] = f2bf(b.z); o[7] = f2bf(b.w);
    *(ushort8*)(out + (size_t)gid * 8) = o;
}

// out[C][R] = bf16(in[R][C]) -- 64x64 LDS tile transpose, z-batched over 4
// weight matrices (1024x1024 each). Pointer selection is block-uniform.
__global__ void transpose_convert_w4(
    const float* __restrict__ w0, const float* __restrict__ w1,
    const float* __restrict__ w2, const float* __restrict__ w3,
    u16* __restrict__ o0, u16* __restrict__ o1,
    u16* __restrict__ o2, u16* __restrict__ o3) {
    __shared__ u16 sT[64][65];
    const int z = blockIdx.z;
    const float* in = (z == 0) ? w0 : (z == 1) ? w1 : (z == 2) ? w2 : w3;
    u16* out = (z == 0) ? o0 : (z == 1) ? o1 : (z == 2) ? o2 : o3;
    const int R = 1024, C = 1024;
    const int c0 = blockIdx.x << 6, r0 = blockIdx.y << 6;
    const int tid = threadIdx.x;
#pragma unroll
    for (int rep = 0; rep < 16; rep++) {
        int idx = rep * 256 + tid;
        int r = idx >> 6, c = idx & 63;
        sT[c][r] = f2bf(in[(size_t)(r0 + r) * C + c0 + c]);
    }
    __syncthreads();
#pragma unroll
    for (int rep = 0; rep < 16; rep++) {
        int idx = rep * 256 + tid;
        int r = idx >> 6, c = idx & 63;
        out[(size_t)(c0 + r) * R + r0 + c] = sT[r][c];
    }
}

// same body, z-batched over the two 4096x2048 projection matrices
__global__ void transpose_convert_p2(
    const float* __restrict__ p0, const float* __restrict__ p1,
    u16* __restrict__ o0, u16* __restrict__ o1) {
    __shared__ u16 sT[64][65];
    const int z = blockIdx.z;
    const float* in = (z == 0) ? p0 : p1;
    u16* out = (z == 0) ? o0 : o1;
    const int R = 4096, C = 2048;
    const int c0 = blockIdx.x << 6, r0 = blockIdx.y << 6;
    const int tid = threadIdx.x;
#pragma unroll
    for (int rep = 0; rep < 16; rep++) {
        int idx = rep * 256 + tid;
        int r = idx >> 6, c = idx & 63;
        sT[c][r] = f2bf(in[(size_t)(r0 + r) * C + c0 + c]);
    }
    __syncthreads();
#pragma unroll
    for (int rep = 0; rep < 16; rep++) {
        int idx = rep * 256 + tid;
        int r = idx >> 6, c = idx & 63;
        out[(size_t)(c0 + r) * R + r0 + c] = sT[r][c];
    }
}

// maskbits[i][w] bit (j&31) = (mask[i][2j+1] != 0), j = resized col index
__global__ void mask_pack(const float* __restrict__ mask, unsigned* __restrict__ mw) {
    int gid = blockIdx.x * 256 + threadIdx.x;      // 4096*2048 threads
    int i = gid >> 11, j = gid & 2047;
    float v = mask[(size_t)i * 4096 + 2 * j + 1];
    unsigned long long b = __ballot(v != 0.0f);
    int lane = threadIdx.x & 63;
    if (lane == 0)       mw[(size_t)i * 64 + (j >> 5)] = (unsigned)b;
    else if (lane == 32) mw[(size_t)i * 64 + (j >> 5)] = (unsigned)(b >> 32);
}

// ---------------- NT GEMM: C[i][j] = sum_k A[i][k]*B[j][k] ----------------
// A [M][K] row-major bf16, B [N][K] row-major bf16. 128x128 tile, BK=32, dbuf LDS.
// grid = (N/128, M/128, batches)

template <bool OUT_BF16, bool ADD_BIAS>
__global__ __launch_bounds__(256) void gemm_nt(
    const u16* __restrict__ A, int lda, long long sA,
    const u16* __restrict__ B, int ldb, long long sB,
    void* __restrict__ Cp, int ldc, long long sC,
    const float* __restrict__ bias, int K) {
    __shared__ __align__(16) u16 lds[2][2][4][128][8];   // [buf][mat][kblk][row][8] = 32KB
    const int bz = blockIdx.z;
    const u16* Ab = A + (size_t)sA * bz;
    const u16* Bb = B + (size_t)sB * bz;
    const int m0 = blockIdx.y << 7, n0 = blockIdx.x << 7;
    const int tid = threadIdx.x, wave = tid >> 6, lane = tid & 63;
    const int kg = lane >> 4, lr = lane & 15;
    const int wr = (wave >> 1) << 6, wc = (wave & 1) << 6;
    const int nT = K >> 5;
    f32x4 acc[4][4] = {};

    // prologue: stage tile 0 into buf 0. wave stages kblk==wave, rows i*64+lane.
#pragma unroll
    for (int i = 0; i < 2; i++) {
        int row = i * 64 + lane;
        GLD16(Ab + (size_t)(m0 + row) * lda + wave * 8, &lds[0][0][wave][i * 64][0]);
        GLD16(Bb + (size_t)(n0 + row) * ldb + wave * 8, &lds[0][1][wave][i * 64][0]);
    }
    for (int t = 0; t < nT; ++t) {
        const int cur = t & 1;
        if (t + 1 < nT) {
            const int nxt = cur ^ 1;
            const int koff = (t + 1) << 5;
#pragma unroll
            for (int i = 0; i < 2; i++) {
                int row = i * 64 + lane;
                GLD16(Ab + (size_t)(m0 + row) * lda + koff + wave * 8, &lds[nxt][0][wave][i * 64][0]);
                GLD16(Bb + (size_t)(n0 + row) * ldb + koff + wave * 8, &lds[nxt][1][wave][i * 64][0]);
            }
        }
        __syncthreads();   // drains vmcnt -> buf[cur] ready
        bf16x8 af[4], bfv[4];
#pragma unroll
        for (int mi = 0; mi < 4; mi++)
            af[mi] = *(const bf16x8*)&lds[cur][0][kg][wr + mi * 16 + lr][0];
#pragma unroll
        for (int ni = 0; ni < 4; ni++)
            bfv[ni] = *(const bf16x8*)&lds[cur][1][kg][wc + ni * 16 + lr][0];
#pragma unroll
        for (int mi = 0; mi < 4; mi++)
#pragma unroll
            for (int ni = 0; ni < 4; ni++)
                acc[mi][ni] = __builtin_amdgcn_mfma_f32_16x16x32_bf16(af[mi], bfv[ni], acc[mi][ni], 0, 0, 0);
        __syncthreads();   // all reads of buf[cur] done before it is re-staged
    }

    if constexpr (OUT_BF16) {
        u16* C = (u16*)Cp + (size_t)sC * bz;
#pragma unroll
        for (int mi = 0; mi < 4; mi++)
#pragma unroll
            for (int ni = 0; ni < 4; ni++)
#pragma unroll
                for (int r = 0; r < 4; r++) {
                    int gr = m0 + wr + mi * 16 + kg * 4 + r;
                    int gc = n0 + wc + ni * 16 + lr;
                    C[(size_t)gr * ldc + gc] = f2bf(acc[mi][ni][r]);
                }
    } else {
        float* C = (float*)Cp + (size_t)sC * bz;
#pragma unroll
        for (int mi = 0; mi < 4; mi++)
#pragma unroll
            for (int ni = 0; ni < 4; ni++)
#pragma unroll
                for (int r = 0; r < 4; r++) {
                    int gr = m0 + wr + mi * 16 + kg * 4 + r;
                    int gc = n0 + wc + ni * 16 + lr;
                    float v = acc[mi][ni][r];
                    if constexpr (ADD_BIAS) v += bias[gc];
                    C[(size_t)gr * ldc + gc] = v;
                }
    }
}

// ---- split-K variant: bz in [0,4) = (bsel = bz>>1, ks = bz&1). bf16 partials.
// Cpart[bz][i][j] = sum_{k in half ks} A[bsel-slice][i][k] * B[bsel-slice][j][k]
__global__ __launch_bounds__(256) void gemm_nt_splitk(
    const u16* __restrict__ A, int lda, long long sAb,
    const u16* __restrict__ B, int ldb, long long sBb,
    u16* __restrict__ Cp, int ldc, long long sC, int K2) {
    __shared__ __align__(16) u16 lds[2][2][4][128][8];
    const int bz = blockIdx.z, bsel = bz >> 1, ks = bz & 1;
    const u16* Ab = A + (size_t)sAb * bsel + (size_t)ks * K2;
    const u16* Bb = B + (size_t)sBb * bsel + (size_t)ks * K2;
    const int m0 = blockIdx.y << 7, n0 = blockIdx.x << 7;
    const int tid = threadIdx.x, wave = tid >> 6, lane = tid & 63;
    const int kg = lane >> 4, lr = lane & 15;
    const int wr = (wave >> 1) << 6, wc = (wave & 1) << 6;
    const int nT = K2 >> 5;
    f32x4 acc[4][4] = {};

#pragma unroll
    for (int i = 0; i < 2; i++) {
        int row = i * 64 + lane;
        GLD16(Ab + (size_t)(m0 + row) * lda + wave * 8, &lds[0][0][wave][i * 64][0]);
        GLD16(Bb + (size_t)(n0 + row) * ldb + wave * 8, &lds[0][1][wave][i * 64][0]);
    }
    for (int t = 0; t < nT; ++t) {
        const int cur = t & 1;
        if (t + 1 < nT) {
            const int nxt = cur ^ 1;
            const int koff = (t + 1) << 5;
#pragma unroll
            for (int i = 0; i < 2; i++) {
                int row = i * 64 + lane;
                GLD16(Ab + (size_t)(m0 + row) * lda + koff + wave * 8, &lds[nxt][0][wave][i * 64][0]);
                GLD16(Bb + (size_t)(n0 + row) * ldb + koff + wave * 8, &lds[nxt][1][wave][i * 64][0]);
            }
        }
        __syncthreads();
        bf16x8 af[4], bfv[4];
#pragma unroll
        for (int mi = 0; mi < 4; mi++)
            af[mi] = *(const bf16x8*)&lds[cur][0][kg][wr + mi * 16 + lr][0];
#pragma unroll
        for (int ni = 0; ni < 4; ni++)
            bfv[ni] = *(const bf16x8*)&lds[cur][1][kg][wc + ni * 16 + lr][0];
#pragma unroll
        for (int mi = 0; mi < 4; mi++)
#pragma unroll
            for (int ni = 0; ni < 4; ni++)
                acc[mi][ni] = __builtin_amdgcn_mfma_f32_16x16x32_bf16(af[mi], bfv[ni], acc[mi][ni], 0, 0, 0);
        __syncthreads();
    }

    u16* C = Cp + (size_t)sC * bz;
#pragma unroll
    for (int mi = 0; mi < 4; mi++)
#pragma unroll
        for (int ni = 0; ni < 4; ni++)
#pragma unroll
            for (int r = 0; r < 4; r++) {
                int gr = m0 + wr + mi * 16 + kg * 4 + r;
                int gc = n0 + wc + ni * 16 + lr;
                C[(size_t)gr * ldc + gc] = f2bf(acc[mi][ni][r]);
            }
}

// dst[d] = bf16( p[(2b)S + r] + p[(2b+1)S + r] ),  d = b*S + r, S = 2^21
__global__ void combine_bf16(const u16* __restrict__ p, u16* __restrict__ dst) {
    int gid = blockIdx.x * 256 + threadIdx.x;   // 524288 threads, 8 elems each
    size_t d = (size_t)gid * 8;
    size_t b = d >> 21, r = d & (((size_t)1 << 21) - 1);
    const ushort8 a = *(const ushort8*)(p + ((b * 2) << 21) + r);
    const ushort8 c = *(const ushort8*)(p + ((b * 2 + 1) << 21) + r);
    ushort8 o;
#pragma unroll
    for (int i = 0; i < 8; i++) o[i] = f2bf(bf2f(a[i]) + bf2f(c[i]));
    *(ushort8*)(dst + d) = o;
}

// ---------------- flash attention over compressed K/V (R17-green, frozen) -----
// Per wave: 16 q rows (q = nrow+lr), loop kp tiles of 32. 2 GLD16/thread;
// stage(nxt); barrier; process(cur); barrier. Mask word t+1 prefetched before
// the barrier. Math/xform/stores = R14/R17-proven.

__global__ __launch_bounds__(256) void attn_kernel(
    const u16* __restrict__ q, const u16* __restrict__ kb,
    const u16* __restrict__ vt, const unsigned* __restrict__ mw,
    u16* __restrict__ ao) {
    __shared__ __align__(16) u16 sK[2][8][32][8];   // [buf][dh8][kp][8] 4KB/buf
    __shared__ __align__(16) u16 sV[2][4][64][8];   // [buf][kp8][dh][8] 4KB/buf
    const int tid = threadIdx.x;
    const int wave = tid >> 6, lane = tid & 63, kg = lane >> 4, lr = lane & 15;
    const int b = blockIdx.x >> 4, h = blockIdx.x & 15;
    const int nrow = (blockIdx.y << 6) + wave * 16;

    const u16* qrow = q + (size_t)(b * 4096 + nrow + lr) * 1024 + h * 64 + kg * 8;
    const bf16x8 aq0 = *(const bf16x8*)qrow;
    const bf16x8 aq1 = *(const bf16x8*)(qrow + 32);
    const u16* kh = kb + (size_t)b * 2048 * 1024 + h * 64;
    const u16* vh = vt + ((size_t)b * 1024 + (size_t)h * 64) * 2048;
    const unsigned* mrow = mw + (size_t)(nrow + lr) * 64;

    // branch-free staging addresses (fixed per thread; only j0 varies)
    const u16* ksrc = kh + (size_t)(lane & 31) * 1024 + (wave * 2 + (lane >> 5)) * 8;
    const u16* vsrc = vh + (size_t)lane * 2048 + wave * 8;

    f32x4 o[4] = {};      // o[f][r] = O[q=lr][dh = f*16 + kg*4 + r] (unnormalized)
    float lsum = 0.0f;
    const bool low16 = (lane & 16) == 0;

    auto stage = [&](int bf, int j0) {
        GLD16(ksrc + (size_t)j0 * 1024, &sK[bf][wave * 2][0][0]);
        GLD16(vsrc + j0, &sV[bf][wave][0][0]);
    };

    auto process = [&](int cur, unsigned wd) {
        const bf16x8 k0a = *(const bf16x8*)&sK[cur][kg][lr][0];
        const bf16x8 k0b = *(const bf16x8*)&sK[cur][4 + kg][lr][0];
        const bf16x8 k1a = *(const bf16x8*)&sK[cur][kg][16 + lr][0];
        const bf16x8 k1b = *(const bf16x8*)&sK[cur][4 + kg][16 + lr][0];
        const bf16x8 v0 = *(const bf16x8*)&sV[cur][kg][lr][0];
        const bf16x8 v1 = *(const bf16x8*)&sV[cur][kg][16 + lr][0];
        const bf16x8 v2 = *(const bf16x8*)&sV[cur][kg][32 + lr][0];
        const bf16x8 v3 = *(const bf16x8*)&sV[cur][kg][48 + lr][0];

        f32x4 s0 = {0.f, 0.f, 0.f, 0.f}, s1 = {0.f, 0.f, 0.f, 0.f};
        s0 = __builtin_amdgcn_mfma_f32_16x16x32_bf16(k0a, aq0, s0, 0, 0, 0);
        s0 = __builtin_amdgcn_mfma_f32_16x16x32_bf16(k0b, aq1, s0, 0, 0, 0);
        s1 = __builtin_amdgcn_mfma_f32_16x16x32_bf16(k1a, aq0, s1, 0, 0, 0);
        s1 = __builtin_amdgcn_mfma_f32_16x16x32_bf16(k1b, aq1, s1, 0, 0, 0);
        const unsigned mb0 = wd >> (kg * 4);
        const unsigned mb1 = wd >> (16 + kg * 4);
        // p = exp2(s * (0.125*log2e)); masked -> 0
        const float C = 0.18033688f;
        float p0[4], p1[4];
#pragma unroll
        for (int r = 0; r < 4; r++) {
            float t0 = ((mb0 >> r) & 1u) ? -1.0e30f : s0[r] * C;
            float t1 = ((mb1 >> r) & 1u) ? -1.0e30f : s1[r] * C;
            p0[r] = fexp2(t0);
            p1[r] = fexp2(t1);
            lsum += p0[r] + p1[r];
        }
        // pack to bf16 pairs: c* hold kp kg*4+{01,23}, d* hold kp 16+kg*4+{01,23}
        unsigned X0 = cvt_pk_bf16(p0[0], p0[1]);
        unsigned X1 = cvt_pk_bf16(p0[2], p0[3]);
        unsigned Y0 = cvt_pk_bf16(p1[0], p1[1]);
        unsigned Y1 = cvt_pk_bf16(p1[2], p1[3]);
        // lane-transpose P^T -> B-frag (lane needs kp slice kg*8..kg*8+7 for q=lr)
        asm volatile("v_permlane32_swap_b32 %0, %1" : "+v"(X0), "+v"(Y0));
        asm volatile("v_permlane32_swap_b32 %0, %1" : "+v"(X1), "+v"(Y1));
        unsigned sX0 = (unsigned)__shfl_xor((int)X0, 16);
        unsigned sY0 = (unsigned)__shfl_xor((int)Y0, 16);
        unsigned sX1 = (unsigned)__shfl_xor((int)X1, 16);
        unsigned sY1 = (unsigned)__shfl_xor((int)Y1, 16);
        uint4v wv;
        wv[0] = low16 ? X0 : sY0;
        wv[1] = low16 ? X1 : sY1;
        wv[2] = low16 ? sX0 : Y0;
        wv[3] = low16 ? sX1 : Y1;
        bf16x8 W = __builtin_bit_cast(bf16x8, wv);
        o[0] = __builtin_amdgcn_mfma_f32_16x16x32_bf16(v0, W, o[0], 0, 0, 0);
        o[1] = __builtin_amdgcn_mfma_f32_16x16x32_bf16(v1, W, o[1], 0, 0, 0);
        o[2] = __builtin_amdgcn_mfma_f32_16x16x32_bf16(v2, W, o[2], 0, 0, 0);
        o[3] = __builtin_amdgcn_mfma_f32_16x16x32_bf16(v3, W, o[3], 0, 0, 0);
    };

    stage(0, 0);
    unsigned wdc = mrow[0];
    for (int t = 0; t < 64; ++t) {
        const int cur = t & 1;
        if (t < 63) stage(cur ^ 1, (t + 1) * 32);
        unsigned wdn = (t < 63) ? mrow[t + 1] : 0u;   // prefetch next mask word
        __syncthreads();   // drains vmcnt -> buf[cur] ready (and wdn)
        process(cur, wdc);
        wdc = wdn;
        __syncthreads();   // all reads of buf[cur] done before re-stage
    }

    lsum += __shfl_xor(lsum, 16);
    lsum += __shfl_xor(lsum, 32);
    const float inv = 1.0f / lsum;

    u16* orow = ao + (size_t)(b * 4096 + nrow + lr) * 1024 + h * 64 + kg * 4;
#pragma unroll
    for (int f = 0; f < 4; f++) {
        uint2v st;
        st[0] = cvt_pk_bf16(o[f][0] * inv, o[f][1] * inv);
        st[1] = cvt_pk_bf16(o[f][2] * inv, o[f][3] * inv);
        *(uint2v*)(orow + f * 16) = st;
    }
}

// ---------------- launcher ----------------

extern "C" void kernel_launch(void* const* d_in, const int* in_sizes, int n_in,
                              void* d_out, int out_size, void* d_ws, size_t ws_size,
                              hipStream_t stream) {
    const float* x    = (const float*)d_in[0];
    const float* mask = (const float*)d_in[1];
    const float* Wq   = (const float*)d_in[2];
    const float* Wk   = (const float*)d_in[3];
    const float* Wv   = (const float*)d_in[4];
    const float* Wo   = (const float*)d_in[5];
    const float* bo   = (const float*)d_in[6];
    const float* pk   = (const float*)d_in[7];
    const float* pv   = (const float*)d_in[8];
    float* out = (float*)d_out;

    char* w = (char*)d_ws;
    auto alloc = [&](size_t bytes) { void* p = w; w += (bytes + 255) & ~(size_t)255; return p; };
    u16* xb   = (u16*)alloc((size_t)8192 * 1024 * 2);
    u16* qb   = (u16*)alloc((size_t)8192 * 1024 * 2);
    u16* xkT  = (u16*)alloc((size_t)1024 * 8192 * 2);   // [xkT|xvT] contiguous:
    u16* xvT  = (u16*)alloc((size_t)1024 * 8192 * 2);   // fused M=2048 GEMM output
    u16* WqT  = (u16*)alloc((size_t)1024 * 1024 * 2);
    u16* WkT  = (u16*)alloc((size_t)1024 * 1024 * 2);   // [WkT|WvT] contiguous:
    u16* WvT  = (u16*)alloc((size_t)1024 * 1024 * 2);   // fused GEMM A-operand
    u16* WoT  = (u16*)alloc((size_t)1024 * 1024 * 2);
    u16* pkT  = (u16*)alloc((size_t)2048 * 4096 * 2);
    u16* pvT  = (u16*)alloc((size_t)2048 * 4096 * 2);
    u16* kbuf = (u16*)alloc((size_t)2 * 2048 * 1024 * 2);
    u16* vtb  = (u16*)alloc((size_t)2 * 1024 * 2048 * 2);
    unsigned* mw = (unsigned*)alloc((size_t)4096 * 64 * 4);
    (void)alloc((size_t)128 * 1024);   // guard pad
    u16* ao   = xb;   // alias: xb dead after q-proj; attention writes after that
    u16* pbuf = qb;   // alias: 4 x 2048x1024 bf16 partials = 16MB, dead before q-proj
    (void)xvT;

    convert_bf16<<<4096, 256, 0, stream>>>(x, xb);
    transpose_convert_w4<<<dim3(16, 16, 4), 256, 0, stream>>>(Wq, Wk, Wv, Wo,
                                                              WqT, WkT, WvT, WoT);
    transpose_convert_p2<<<dim3(32, 64, 2), 256, 0, stream>>>(pk, pv, pkT, pvT);
    mask_pack<<<32768, 256, 0, stream>>>(mask, mw);

    // fused [xkT|xvT] = [WkT|WvT](M=2048) x B(xb) : [2048,8192], one launch
    gemm_nt<true, false><<<dim3(64, 16, 1), 256, 0, stream>>>(WkT, 1024, 0, xb, 1024, 0, xkT, 8192, 0, nullptr, 1024);

    // k[b] = proj_k^T @ xk[b] : split-K x2 -> bf16 partials -> combine
    gemm_nt_splitk<<<dim3(8, 16, 4), 256, 0, stream>>>(pkT, 4096, 0, xkT, 8192, 4096,
                                                       pbuf, 1024, (long long)1 << 21, 2048);
    combine_bf16<<<2048, 256, 0, stream>>>(pbuf, kbuf);
    // vT[b] = xv[b]^T @ proj_v : split-K x2
    gemm_nt_splitk<<<dim3(16, 8, 4), 256, 0, stream>>>(xvT, 8192, 4096, pvT, 4096, 0,
                                                       pbuf, 2048, (long long)1 << 21, 2048);
    combine_bf16<<<2048, 256, 0, stream>>>(pbuf, vtb);

    // q = x @ Wq (runs AFTER combines: qb overlays pbuf)
    gemm_nt<true, false><<<dim3(8, 64, 1), 256, 0, stream>>>(xb, 1024, 0, WqT, 1024, 0, qb, 1024, 0, nullptr, 1024);

    // grid (bh, qchunk): consecutive blocks differ in bh -> XCD = bh%8 (L2 locality)
    attn_kernel<<<dim3(32, 64), 256, 0, stream>>>(qb, kbuf, vtb, mw, ao);

    // out = ao @ Wo + bo (f32 out; fully overwritten each call)
    gemm_nt<false, true><<<dim3(8, 64, 1), 256, 0, stream>>>(ao, 1024, 0, WoT, 1024, 0, out, 1024, 0, bo, 1024);
}